// Round 14
// baseline (2459.200 us; speedup 1.0000x reference)
//
#include <hip/hip_runtime.h>
#include <math.h>

#define XD 64
#define SEQL 2048
#define NB 32
#define DT_C  (1.0f/1024.0f)
#define EPS_C 1e-4f
#define LD 68
#define LOG2PI 1.8378770664093453f
#define CHUNK 8
#define NCH 256

// ---------------- workspace offsets (floats) ----------------
#define OFF_PARTIAL 0u
#define OFF_MEAN    32768u
#define OFF_STD     32832u
#define OFF_Q       32896u
#define OFF_R       36992u
#define OFF_VM      41088u
#define OFF_QP      45184u
#define OFF_RIREG   49280u
#define OFF_LOGDET  53376u
#define OFF_CHAIN   53440u                      /* 12*16384 */
#define OFF_POW     250048u                     /* 64*16384 */
#define OFF_BOUNDS  1298624u                    /* 33*8192 */
#define OFF_K       1568960u                    /* 2048*4096 */
#define OFF_AEFF    9957568u                    /* 2048*4096 */
#define OFF_UV      18346176u                   /* 2048*8192 ; Kg/Sinv overlay; OPS2 aliases here pre-uvwalk */
#define OFF_G       35123392u                   /* 2048*4096 */
#define OFF_B       43512000u                   /* 2048*2048 */
#define OFF_OPS2    OFF_UV                      /* 2*256*12288 aliased into UV (dead until uvwalk) */
#define OFF_OPS3G   47706304u                   /* 2*256*4096 */
#define OFF_OPS3B   49803456u                   /* 2*256*2048 */
#define OFF_SB2     50852032u                   /* 256*8192 */
#define OFF_XB      52949184u                   /* 256*2048 */
#define OFF_QUAD    53473472u                   /* 2048 */
#define OFF_COST    53475520u                   /* 2048*32 */
#define OFF_BRI     53541056u                   /* 4096 : B @ inv(R+eps I) */

// ---------------- output offsets (floats) ----------------
#define OOFF_XF 2
#define OOFF_U  4194306
#define OOFF_YP 8388610
#define OOFF_YN 12582914

// =====================================================================
// 64x64 matmul helpers: 256 threads, 16 outputs/thread (4x4 tile).
// out = alpha*(op(A)@op(B)) [+ addC]
// =====================================================================
template<int KD>
__device__ __forceinline__ void mmNN(int t, float* __restrict__ out, int ldo,
    const float* __restrict__ A, int lda, const float* __restrict__ B, int ldb,
    const float* __restrict__ addC = nullptr, int ldc = 0, float alpha = 1.0f)
{
  const int r0 = (t >> 4) << 2, c0 = (t & 15) << 2;
  float acc[4][4] = {};
  for (int k = 0; k < KD; k += 4) {
    float a_[4][4];
    #pragma unroll
    for (int i = 0; i < 4; ++i) {
      const float4 x = *(const float4*)&A[(r0+i)*lda + k];
      a_[i][0]=x.x; a_[i][1]=x.y; a_[i][2]=x.z; a_[i][3]=x.w;
    }
    #pragma unroll
    for (int kk = 0; kk < 4; ++kk) {
      const float4 bv = *(const float4*)&B[(k+kk)*ldb + c0];
      #pragma unroll
      for (int i = 0; i < 4; ++i) {
        const float a = a_[i][kk];
        acc[i][0] += a*bv.x; acc[i][1] += a*bv.y; acc[i][2] += a*bv.z; acc[i][3] += a*bv.w;
      }
    }
  }
  #pragma unroll
  for (int i = 0; i < 4; ++i)
    #pragma unroll
    for (int j = 0; j < 4; ++j) {
      float v = alpha*acc[i][j];
      if (addC) v += addC[(r0+i)*ldc + (c0+j)];
      out[(r0+i)*ldo + (c0+j)] = v;
    }
}

template<int KD>
__device__ __forceinline__ void mmTA(int t, float* __restrict__ out, int ldo,
    const float* __restrict__ A, int lda, const float* __restrict__ B, int ldb,
    const float* __restrict__ addC = nullptr, int ldc = 0, float alpha = 1.0f)
{ // out = A^T @ B  (A is KD x 64)
  const int r0 = (t >> 4) << 2, c0 = (t & 15) << 2;
  float acc[4][4] = {};
  for (int k = 0; k < KD; k += 4) {
    #pragma unroll
    for (int kk = 0; kk < 4; ++kk) {
      const float4 av4 = *(const float4*)&A[(k+kk)*lda + r0];
      const float4 bv4 = *(const float4*)&B[(k+kk)*ldb + c0];
      const float av[4] = {av4.x, av4.y, av4.z, av4.w};
      const float bv[4] = {bv4.x, bv4.y, bv4.z, bv4.w};
      #pragma unroll
      for (int i = 0; i < 4; ++i)
        #pragma unroll
        for (int j = 0; j < 4; ++j)
          acc[i][j] += av[i]*bv[j];
    }
  }
  #pragma unroll
  for (int i = 0; i < 4; ++i)
    #pragma unroll
    for (int j = 0; j < 4; ++j) {
      float v = alpha*acc[i][j];
      if (addC) v += addC[(r0+i)*ldc + (c0+j)];
      out[(r0+i)*ldo + (c0+j)] = v;
    }
}

template<int KD>
__device__ __forceinline__ void mmTB(int t, float* __restrict__ out, int ldo,
    const float* __restrict__ A, int lda, const float* __restrict__ B, int ldb,
    const float* __restrict__ addC = nullptr, int ldc = 0, float alpha = 1.0f)
{ // out = A @ B^T  (B is 64 x KD)
  const int r0 = (t >> 4) << 2, c0 = (t & 15) << 2;
  float acc[4][4] = {};
  for (int k = 0; k < KD; k += 4) {
    float a_[4][4], b_[4][4];
    #pragma unroll
    for (int i = 0; i < 4; ++i) {
      const float4 x = *(const float4*)&A[(r0+i)*lda + k];
      a_[i][0]=x.x; a_[i][1]=x.y; a_[i][2]=x.z; a_[i][3]=x.w;
    }
    #pragma unroll
    for (int j = 0; j < 4; ++j) {
      const float4 x = *(const float4*)&B[(c0+j)*ldb + k];
      b_[j][0]=x.x; b_[j][1]=x.y; b_[j][2]=x.z; b_[j][3]=x.w;
    }
    #pragma unroll
    for (int i = 0; i < 4; ++i)
      #pragma unroll
      for (int j = 0; j < 4; ++j)
        acc[i][j] += a_[i][0]*b_[j][0] + a_[i][1]*b_[j][1] + a_[i][2]*b_[j][2] + a_[i][3]*b_[j][3];
  }
  #pragma unroll
  for (int i = 0; i < 4; ++i)
    #pragma unroll
    for (int j = 0; j < 4; ++j) {
      float v = alpha*acc[i][j];
      if (addC) v += addC[(r0+i)*ldc + (c0+j)];
      out[(r0+i)*ldo + (c0+j)] = v;
    }
}

// b_out = 0.5*(X + X^T) tile-based (4x4 tiles, float4 row-major accesses).
__device__ __forceinline__ void symTile(int t, float* __restrict__ outb, const float* __restrict__ X)
{
  const int r0 = (t >> 4) << 2, c0 = (t & 15) << 2;
  float xa[4][4], xb[4][4];
  #pragma unroll
  for (int i = 0; i < 4; ++i) {
    const float4 u = *(const float4*)&X[(r0+i)*LD + c0];
    xa[i][0]=u.x; xa[i][1]=u.y; xa[i][2]=u.z; xa[i][3]=u.w;
    const float4 v = *(const float4*)&X[(c0+i)*LD + r0];
    xb[i][0]=v.x; xb[i][1]=v.y; xb[i][2]=v.z; xb[i][3]=v.w;
  }
  #pragma unroll
  for (int i = 0; i < 4; ++i) {
    float4 o;
    o.x = 0.5f*(xa[i][0] + xb[0][i]);
    o.y = 0.5f*(xa[i][1] + xb[1][i]);
    o.z = 0.5f*(xa[i][2] + xb[2][i]);
    o.w = 0.5f*(xa[i][3] + xb[3][i]);
    *(float4*)&outb[(r0+i)*LD + c0] = o;
  }
}

// 32x64 = (32xKD)@(KDx64) variants: 256 threads, 8 outputs (2x4 tile)
template<int KD>
__device__ __forceinline__ void mm32NN(int t, float* __restrict__ out, int ldo,
    const float* __restrict__ A, int lda, const float* __restrict__ B, int ldb,
    const float* __restrict__ addC = nullptr, int ldc = 0, float alpha = 1.0f)
{
  const int r0 = (t >> 4) << 1, c0 = (t & 15) << 2;
  float acc[2][4] = {};
  for (int k = 0; k < KD; k += 4) {
    float a_[2][4];
    #pragma unroll
    for (int i = 0; i < 2; ++i) {
      const float4 x = *(const float4*)&A[(r0+i)*lda + k];
      a_[i][0]=x.x; a_[i][1]=x.y; a_[i][2]=x.z; a_[i][3]=x.w;
    }
    #pragma unroll
    for (int kk = 0; kk < 4; ++kk) {
      const float4 bv = *(const float4*)&B[(k+kk)*ldb + c0];
      #pragma unroll
      for (int i = 0; i < 2; ++i) {
        const float a = a_[i][kk];
        acc[i][0] += a*bv.x; acc[i][1] += a*bv.y; acc[i][2] += a*bv.z; acc[i][3] += a*bv.w;
      }
    }
  }
  #pragma unroll
  for (int i = 0; i < 2; ++i)
    #pragma unroll
    for (int j = 0; j < 4; ++j) {
      float v = alpha*acc[i][j];
      if (addC) v += addC[(r0+i)*ldc + (c0+j)];
      out[(r0+i)*ldo + (c0+j)] = v;
    }
}

template<int KD>
__device__ __forceinline__ void mm32TB(int t, float* __restrict__ out, int ldo,
    const float* __restrict__ A, size_t lda, const float* __restrict__ B, int ldb,
    const float* __restrict__ addC = nullptr, size_t ldc = 0, float alpha = 1.0f)
{ // out = A @ B^T
  const int r0 = (t >> 4) << 1, c0 = (t & 15) << 2;
  float acc[2][4] = {};
  for (int k = 0; k < KD; k += 4) {
    float a_[2][4], b_[4][4];
    #pragma unroll
    for (int i = 0; i < 2; ++i) {
      const float4 x = *(const float4*)&A[(size_t)(r0+i)*lda + k];
      a_[i][0]=x.x; a_[i][1]=x.y; a_[i][2]=x.z; a_[i][3]=x.w;
    }
    #pragma unroll
    for (int j = 0; j < 4; ++j) {
      const float4 x = *(const float4*)&B[(c0+j)*ldb + k];
      b_[j][0]=x.x; b_[j][1]=x.y; b_[j][2]=x.z; b_[j][3]=x.w;
    }
    #pragma unroll
    for (int i = 0; i < 2; ++i)
      #pragma unroll
      for (int j = 0; j < 4; ++j)
        acc[i][j] += a_[i][0]*b_[j][0] + a_[i][1]*b_[j][1] + a_[i][2]*b_[j][2] + a_[i][3]*b_[j][3];
  }
  #pragma unroll
  for (int i = 0; i < 2; ++i)
    #pragma unroll
    for (int j = 0; j < 4; ++j) {
      float v = alpha*acc[i][j];
      if (addC) v += addC[(size_t)(r0+i)*ldc + (c0+j)];
      out[(r0+i)*ldo + (c0+j)] = v;
    }
}

// Gauss-Jordan (no pivoting): RHS <- Am^{-1} RHS ; destroys Am. 256 threads.
// Used only in the single-block k_setup (cost negligible).
__device__ __forceinline__ void gj64(int t, float* __restrict__ Am, float* __restrict__ R)
{
  const int r = t >> 2;
  const int c0 = (t & 3) << 4;
  for (int k = 0; k < 64; ++k) {
    __syncthreads();
    const float pv = Am[k*LD + k];
    const float f = Am[r*LD + k] / pv;
    if (r != k) {
      #pragma unroll
      for (int c = 0; c < 16; c += 4) {
        float4 ak = *(const float4*)&Am[k*LD + c0 + c];
        float4 ar = *(float4*)&Am[r*LD + c0 + c];
        ar.x -= f*ak.x; ar.y -= f*ak.y; ar.z -= f*ak.z; ar.w -= f*ak.w;
        *(float4*)&Am[r*LD + c0 + c] = ar;
        float4 rk = *(const float4*)&R[k*LD + c0 + c];
        float4 rr = *(float4*)&R[r*LD + c0 + c];
        rr.x -= f*rk.x; rr.y -= f*rk.y; rr.z -= f*rk.z; rr.w -= f*rk.w;
        *(float4*)&R[r*LD + c0 + c] = rr;
      }
    }
  }
  __syncthreads();
  const float dinv = 1.0f / Am[r*LD + r];
  #pragma unroll
  for (int c = 0; c < 16; c += 4) {
    float4 rr = *(float4*)&R[r*LD + c0 + c];
    rr.x *= dinv; rr.y *= dinv; rr.z *= dinv; rr.w *= dinv;
    *(float4*)&R[r*LD + c0 + c] = rr;
  }
  __syncthreads();
}

// =====================================================================
// Blocked Gauss-Jordan, 8x8 pivot blocks, IN-PLACE panel, REDUNDANT
// per-wave diagonal inverse: R <- Am^{-1} R ; destroys Am.
// 256 threads, 3 barriers per block-step. Multiplier loads hoisted to
// block-step start. HW-verified lineage (R10/R11/R12).
// =====================================================================
__device__ __forceinline__ void gjb8(int t, float* __restrict__ Am, float* __restrict__ R)
{
  const int r  = t >> 2;           // row 0..63
  const int c0 = (t & 3) << 4;     // 16-col quadrant
  const int j2 = t >> 5;           // pivot row this thread writes (0..7)
  const int cc = (t & 31) << 2;    // combined col (Am cols 0..63, R cols 64..127)
  const int lane = t & 63;
  const int li = lane >> 3, lj = lane & 7;
  for (int kb = 0; kb < 8; ++kb) {
    const int K = kb << 3;
    __syncthreads();               // prev trailing update complete
    const bool inK = ((unsigned)(r - K)) < 8u;
    float4 f0 = make_float4(0.f,0.f,0.f,0.f), f1 = f0;
    if (!inK) {
      f0 = *(const float4*)&Am[r*LD + K];
      f1 = *(const float4*)&Am[r*LD + K + 4];
    }
    // ---- every wave: W = inv(Am[K..K+7][K..K+7]) in registers ----
    float a = Am[(K+li)*LD + K + lj];
    float w = (li == lj) ? 1.0f : 0.0f;
    #pragma unroll
    for (int p = 0; p < 8; ++p) {
      const float pv  = __shfl(a, p*8 + p, 64);
      const float pvr = __builtin_amdgcn_rcpf(pv);
      const float aip = __shfl(a, li*8 + p, 64);
      const float apj = __shfl(a, p*8 + lj, 64);
      const float wpj = __shfl(w, p*8 + lj, 64);
      const float fi  = aip * pvr;
      if (li == p) { a *= pvr; w *= pvr; }
      else         { a -= fi * apj; w -= fi * wpj; }
    }
    float wrow[8];
    #pragma unroll
    for (int m = 0; m < 8; ++m) wrow[m] = __shfl(w, j2*8 + m, 64);
    // ---- panel = W @ old rows(K..K+7) of [Am | R] into registers ----
    const int c4 = cc & 63;
    float* srcB = (cc < 64) ? Am : R;
    float4 acc = make_float4(0.f, 0.f, 0.f, 0.f);
    #pragma unroll
    for (int m = 0; m < 8; ++m) {
      const float4 rv = *(const float4*)&srcB[(K+m)*LD + c4];
      acc.x += wrow[m]*rv.x; acc.y += wrow[m]*rv.y; acc.z += wrow[m]*rv.z; acc.w += wrow[m]*rv.w;
    }
    __syncthreads();               // all readers done with old pivot rows
    *(float4*)&srcB[(K+j2)*LD + c4] = acc;
    __syncthreads();               // new pivot rows visible
    // ---- rank-8 trailing update (non-pivot rows only) ----
    if (!inK) {
      const float fj[8] = {f0.x, f0.y, f0.z, f0.w, f1.x, f1.y, f1.z, f1.w};
      #pragma unroll
      for (int c = 0; c < 16; c += 4) {
        const int cab = c0 + c;
        if (cab >= K + 8) {
          float4 v = *(float4*)&Am[r*LD + cab];
          #pragma unroll
          for (int j = 0; j < 8; ++j) {
            const float4 p4 = *(const float4*)&Am[(K+j)*LD + cab];
            v.x -= fj[j]*p4.x; v.y -= fj[j]*p4.y; v.z -= fj[j]*p4.z; v.w -= fj[j]*p4.w;
          }
          *(float4*)&Am[r*LD + cab] = v;
        }
      }
      #pragma unroll
      for (int c = 0; c < 16; c += 4) {
        const int cab = c0 + c;
        float4 v = *(float4*)&R[r*LD + cab];
        #pragma unroll
        for (int j = 0; j < 8; ++j) {
          const float4 p4 = *(const float4*)&R[(K+j)*LD + cab];
          v.x -= fj[j]*p4.x; v.y -= fj[j]*p4.y; v.z -= fj[j]*p4.z; v.w -= fj[j]*p4.w;
        }
        *(float4*)&R[r*LD + cab] = v;
      }
    }
  }
  __syncthreads();
}

// =====================================================================
// Kernels
// =====================================================================

__global__ __launch_bounds__(256) void k_stats(const float* __restrict__ y, float* __restrict__ ws)
{
  __shared__ float sbuf[4][128];
  const int t = threadIdx.x, blk = blockIdx.x;
  const int d = t & 63, g = t >> 6;
  float s = 0.f, s2 = 0.f;
  for (int r = g; r < 256; r += 4) {
    const float v = y[(size_t)(blk*256 + r)*64 + d];
    s += v; s2 += v*v;
  }
  sbuf[g][d] = s; sbuf[g][64+d] = s2;
  __syncthreads();
  if (t < 128) ws[OFF_PARTIAL + (size_t)blk*128 + t] = sbuf[0][t]+sbuf[1][t]+sbuf[2][t]+sbuf[3][t];
}

__global__ __launch_bounds__(256) void k_setup(
    const float* __restrict__ A, const float* __restrict__ Bi,
    const float* __restrict__ LQ, const float* __restrict__ LR,
    const float* __restrict__ LV, const float* __restrict__ LQp,
    float* __restrict__ ws)
{
  __shared__ float b1[64*LD], b2[64*LD], b3[64*LD], b4[64*LD], bQ[64*LD];
  __shared__ float sred[128];
  const int t = threadIdx.x;

  if (t < 128) {
    float acc = 0.f;
    for (int p = 0; p < 256; ++p) acc += ws[OFF_PARTIAL + (size_t)p*128 + t];
    sred[t] = acc;
  }
  __syncthreads();
  if (t < 64) {
    const float mean = sred[t] * (1.0f/65536.0f);
    const float var = (sred[64+t] - 65536.0f*mean*mean) * (1.0f/65535.0f);
    ws[OFF_MEAN + t] = mean;
    ws[OFF_STD + t] = sqrtf(var);
  }

  mmTB<64>(t, bQ, LD, LQ, 64, LQ, 64);              // Q
  mmTB<64>(t, b3, LD, LR, 64, LR, 64);              // R
  mmTB<64>(t, ws+OFF_VM, 64, LV, 64, LV, 64);       // V
  mmTB<64>(t, ws+OFF_QP, 64, LQp, 64, LQp, 64);     // Q_proc
  __syncthreads();
  for (int idx = t; idx < 4096; idx += 256) {
    const int r = idx>>6, c = idx&63;
    ws[OFF_Q + idx] = bQ[r*LD+c];
    ws[OFF_R + idx] = b3[r*LD+c];
    b1[r*LD+c] = b3[r*LD+c] + ((r==c)?EPS_C:0.f);
    b2[r*LD+c] = (r==c)?1.f:0.f;
  }
  gj64(t, b1, b2);                                   // b2 = inv(R + eps I)
  mmNN<64>(t, b4, LD, Bi, 64, b2, LD);               // b4 = BRI = B @ inv(R+eps)
  __syncthreads();
  for (int idx = t; idx < 4096; idx += 256) {
    ws[OFF_RIREG + idx] = b2[(idx>>6)*LD+(idx&63)];
    ws[OFF_BRI + idx]   = b4[(idx>>6)*LD+(idx&63)];
  }
  __syncthreads();
  for (int idx = t; idx < 4096; idx += 256) {
    const int r = idx>>6, c = idx&63;
    b1[r*LD+c] = b3[r*LD+c];
    b2[r*LD+c] = (r==c)?1.f:0.f;
  }
  gj64(t, b1, b2);                                   // b2 = inv(R)
  mmTB<64>(t, b3, LD, b2, LD, Bi, 64);               // b3 = Rinv @ B^T
  __syncthreads();
  mmNN<64>(t, b4, LD, Bi, 64, b3, LD);               // b4 = B Rinv B^T
  mmTB<64>(t, b1, LD, LV, 64, LV, 64);               // b1 = V (for logdet)
  __syncthreads();
  if (t < 64) b1[t*LD+t] += EPS_C;
  {
    const int r = t >> 2, c0 = (t & 3) << 4;
    float lsum = 0.f;
    for (int k = 0; k < 64; ++k) {
      __syncthreads();
      const float pv = b1[k*LD+k];
      lsum += logf(pv);
      const float f = b1[r*LD+k] / pv;
      if (r != k) {
        #pragma unroll
        for (int c = 0; c < 16; c += 4) {
          float4 ak = *(const float4*)&b1[k*LD+c0+c];
          float4 ar = *(float4*)&b1[r*LD+c0+c];
          ar.x -= f*ak.x; ar.y -= f*ak.y; ar.z -= f*ak.z; ar.w -= f*ak.w;
          *(float4*)&b1[r*LD+c0+c] = ar;
        }
      }
    }
    if (t == 0) ws[OFF_LOGDET] = lsum;
  }
  __syncthreads();
  // M = I + DT*[[A, -BRB],[-Q, -A^T]]  -> chain[0]
  float* M0 = ws + OFF_CHAIN;
  for (int idx = t; idx < 16384; idx += 256) {
    const int i = idx >> 7, j = idx & 127;
    float v;
    if (i < 64) v = (j < 64) ? (((i==j)?1.f:0.f) + DT_C*A[i*64+j]) : (-DT_C*b4[i*LD + (j-64)]);
    else        v = (j < 64) ? (-DT_C*bQ[(i-64)*LD + j]) : (((i==j)?1.f:0.f) - DT_C*A[(j-64)*64 + (i-64)]);
    M0[idx] = v;
  }
  for (int idx = t; idx < 16384; idx += 256) {
    const int i = idx >> 7, j = idx & 127;
    ws[OFF_POW + idx] = (i==j)?1.f:0.f;              // M^0 = I
  }
  for (int idx = t; idx < 8192; idx += 256) {
    const int i = idx >> 6, j = idx & 63;
    ws[OFF_BOUNDS + idx] = (i < 64) ? ((i==j)?1.f:0.f) : bQ[(i-64)*LD + j];   // S0 = [I; Q]
  }
}

__global__ __launch_bounds__(256) void k_yn(const float* __restrict__ y, const float* __restrict__ ws, float* __restrict__ out)
{
  const size_t i0 = ((size_t)blockIdx.x*256 + threadIdx.x)*4;
  const int d = (int)(i0 & 63);
  const float4 v = *(const float4*)&y[i0];
  const float4 m = *(const float4*)&ws[OFF_MEAN + d];
  const float4 s = *(const float4*)&ws[OFF_STD + d];
  float* o = out + OOFF_YN + i0;
  o[0] = (v.x - m.x)/(s.x + EPS_C);
  o[1] = (v.y - m.y)/(s.y + EPS_C);
  o[2] = (v.z - m.z)/(s.z + EPS_C);
  o[3] = (v.w - m.w)/(s.w + EPS_C);
}

__global__ __launch_bounds__(1024) void k_sqchain(float* __restrict__ chain)
{ // chain[j] = chain[j-1]^2 for j=1..11, one block, LDS double-buffered
  __shared__ float bufA[128*128], bufB[128*128];
  const int t = threadIdx.x;
  for (int idx = t; idx < 16384; idx += 1024) bufA[idx] = chain[idx];
  __syncthreads();
  float* Abuf = bufA; float* Bbuf = bufB;
  for (int j = 1; j <= 11; ++j) {
    float* dst = chain + (size_t)j*16384;
    const int c0 = (t & 31) << 2;
    #pragma unroll
    for (int g = 0; g < 4; ++g) {
      const int r = (t >> 5) + (g << 5);
      float a0=0.f, a1=0.f, a2=0.f, a3=0.f;
      for (int k = 0; k < 128; k += 4) {
        const float4 a4 = *(const float4*)&Abuf[r*128 + k];
        const float av[4] = {a4.x, a4.y, a4.z, a4.w};
        #pragma unroll
        for (int kk = 0; kk < 4; ++kk) {
          const float4 b4 = *(const float4*)&Abuf[(k+kk)*128 + c0];
          a0 += av[kk]*b4.x; a1 += av[kk]*b4.y; a2 += av[kk]*b4.z; a3 += av[kk]*b4.w;
        }
      }
      float4 o; o.x=a0; o.y=a1; o.z=a2; o.w=a3;
      *(float4*)&Bbuf[r*128 + c0] = o;
      *(float4*)&dst[r*128 + c0] = o;
    }
    __syncthreads();
    float* tmp = Abuf; Abuf = Bbuf; Bbuf = tmp;
  }
}

__global__ __launch_bounds__(256) void k_powbounds(const float* __restrict__ chain, float* __restrict__ ws, int level)
{ // fused: blocks [0, 4<<level) = pow level; blocks [4<<level, 6<<level) = bounds level
  const int nbp = 4 << level;
  const int t = threadIdx.x;
  if ((int)blockIdx.x < nbp) {
    // ---- pow: powt[i + 2^level] = chain[level] @ powt[i] ----
    const float* chainj = chain + (size_t)level*16384;
    float* powt = ws + OFF_POW;
    const int i = blockIdx.x >> 2, sub = blockIdx.x & 3;
    const float* Bm = powt + (size_t)i*16384;
    float* D = powt + (size_t)(i + (1<<level))*16384;
    const int r0 = sub*32 + ((t >> 4) << 1);
    const int c0 = (t & 15) << 3;
    float acc[2][8] = {};
    for (int k = 0; k < 128; k += 4) {
      float a_[2][4];
      {
        const float4 x = *(const float4*)&chainj[r0*128 + k];
        a_[0][0]=x.x; a_[0][1]=x.y; a_[0][2]=x.z; a_[0][3]=x.w;
        const float4 y2 = *(const float4*)&chainj[(r0+1)*128 + k];
        a_[1][0]=y2.x; a_[1][1]=y2.y; a_[1][2]=y2.z; a_[1][3]=y2.w;
      }
      #pragma unroll
      for (int kk = 0; kk < 4; ++kk) {
        const float4 b0 = *(const float4*)&Bm[(k+kk)*128 + c0];
        const float4 b1v = *(const float4*)&Bm[(k+kk)*128 + c0 + 4];
        #pragma unroll
        for (int i2 = 0; i2 < 2; ++i2) {
          const float a = a_[i2][kk];
          acc[i2][0] += a*b0.x; acc[i2][1] += a*b0.y; acc[i2][2] += a*b0.z; acc[i2][3] += a*b0.w;
          acc[i2][4] += a*b1v.x; acc[i2][5] += a*b1v.y; acc[i2][6] += a*b1v.z; acc[i2][7] += a*b1v.w;
        }
      }
    }
    #pragma unroll
    for (int i2 = 0; i2 < 2; ++i2)
      #pragma unroll
      for (int j = 0; j < 8; ++j)
        D[(r0+i2)*128 + c0 + j] = acc[i2][j];
  } else {
    // ---- bounds: bounds[k + 2^level] = chain[6+level] @ bounds[k] ----
    const int bb = blockIdx.x - nbp;
    const int kb = bb >> 1, sub = bb & 1;
    const int dsti = kb + (1 << level);
    if (dsti > 32) return;
    const float* chainp = chain + (size_t)(6+level)*16384;
    const float* S = ws + OFF_BOUNDS + (size_t)kb*8192;
    float* D = ws + OFF_BOUNDS + (size_t)dsti*8192;
    const int r0 = sub*64 + ((t >> 4) << 2);
    const int c0 = (t & 15) << 2;
    float acc[4][4] = {};
    for (int k = 0; k < 128; k += 4) {
      float a_[4][4];
      #pragma unroll
      for (int i = 0; i < 4; ++i) {
        const float4 x = *(const float4*)&chainp[(r0+i)*128 + k];
        a_[i][0]=x.x; a_[i][1]=x.y; a_[i][2]=x.z; a_[i][3]=x.w;
      }
      #pragma unroll
      for (int kk = 0; kk < 4; ++kk) {
        const float4 bv = *(const float4*)&S[(k+kk)*64 + c0];
        #pragma unroll
        for (int i = 0; i < 4; ++i) {
          const float a = a_[i][kk];
          acc[i][0] += a*bv.x; acc[i][1] += a*bv.y; acc[i][2] += a*bv.z; acc[i][3] += a*bv.w;
        }
      }
    }
    #pragma unroll
    for (int i = 0; i < 4; ++i)
      #pragma unroll
      for (int j = 0; j < 4; ++j)
        D[(r0+i)*64 + c0 + j] = acc[i][j];
  }
}

__global__ __launch_bounds__(256) void k_lqr(const float* __restrict__ Ain, const float* __restrict__ Bin, float* __restrict__ ws)
{ // per-t: S = M^r @ SB_k ; Uinv ; X = V Uinv ; P ; bp ; {K, BRIbp} ; coalesced stores
  __shared__ float b1[64*LD], b2[64*LD], b3[64*LD];
  const int t = threadIdx.x, tt = blockIdx.x;
  const int tp1 = tt + 1, kc = tp1 >> 6, rr = tp1 & 63;
  const float* Mr = ws + OFF_POW + (size_t)rr*16384;
  const float* SB = ws + OFF_BOUNDS + (size_t)kc*8192;
  mmNN<128>(t, b1, LD, Mr, 128, SB, 64);            // U = (Mr@SB)[0:64]
  mmNN<128>(t, b3, LD, Mr + 8192, 128, SB, 64);     // V = (Mr@SB)[64:128]
  for (int idx = t; idx < 4096; idx += 256) {
    const int r = idx>>6, c = idx&63;
    b2[r*LD+c] = (r==c)?1.f:0.f;
  }
  gjb8(t, b1, b2);                                  // b2 = U^{-1}  (leading sync inside)
  mmNN<64>(t, b1, LD, b3, LD, b2, LD);              // b1 = X = V @ Uinv
  __syncthreads();
  symTile(t, b3, b1);                               // b3 = P = sym(X)
  __syncthreads();
  mmTA<64>(t, b1, LD, Bin, 64, b3, LD);             // b1 = bp = B^T P
  __syncthreads();
  mmNN<64>(t, b2, LD, ws+OFF_RIREG, 64, b1, LD);    // b2 = K = RIREG @ bp
  mmNN<64>(t, b3, LD, ws+OFF_BRI, 64, b1, LD);      // b3 = BRI @ bp
  __syncthreads();
  float* Kout = ws + OFF_K + (size_t)tt*4096;
  float* Ae   = ws + OFF_AEFF + (size_t)tt*4096;
  for (int idx = t; idx < 4096; idx += 256) {
    const int p = (idx>>6)*LD + (idx&63);
    Kout[idx] = b2[p];
    Ae[idx]   = Ain[idx] - b3[p];
  }
}

__global__ __launch_bounds__(1024) void k_ops2(const float* __restrict__ ws_aeff, const float* __restrict__ ws_qp, float* __restrict__ dstE)
{ // per-chunk KF transfer-operator product (E,W,F)
  __shared__ float E[64*LD], W[64*LD], F[64*LD], T1[64*LD], T2[64*LD], T3[64*LD], T4[64*LD];
  const int t = threadIdx.x, c = blockIdx.x, g = t >> 8, tl = t & 255;
  for (int idx = t; idx < 4096; idx += 1024) {
    const int r = idx>>6, cc = idx&63; const float id = (r==cc)?1.f:0.f;
    E[r*LD+cc] = id; W[r*LD+cc] = 0.f; F[r*LD+cc] = id;
  }
  __syncthreads();
  for (int s = 0; s < CHUNK; ++s) {
    const float* Ae = ws_aeff + ((size_t)c*CHUNK + s)*4096;
    if (g == 0)      mmNN<64>(tl, T1, LD, Ae, 64, E, LD);
    else if (g == 1) mmNN<64>(tl, T2, LD, Ae, 64, W, LD);
    else if (g == 2) mmNN<64>(tl, T3, LD, ws_qp, 64, F, LD);
    else             mmTA<64>(tl, T4, LD, Ae, 64, F, LD);
    __syncthreads();
    for (int idx = t; idx < 4096; idx += 1024) {
      const int p = (idx>>6)*LD + (idx&63);
      E[p] += DT_C*T1[p];
      W[p] += DT_C*(T2[p] + T3[p]);
      F[p] -= DT_C*T4[p];
    }
    __syncthreads();
  }
  float* dst = dstE + (size_t)c*12288;
  for (int idx = t; idx < 4096; idx += 1024) {
    const int p = (idx>>6)*LD + (idx&63);
    dst[idx] = E[p]; dst[4096+idx] = W[p]; dst[8192+idx] = F[p];
  }
}

__global__ __launch_bounds__(1024) void k_scan2(const float* __restrict__ src, float* __restrict__ dst, int s)
{ // Hillis-Steele compose of (E,W,F) ops; op[i] (later) after op[i-s] (earlier)
  __shared__ float t1[64*LD], t2[64*LD];
  const int i = blockIdx.x, t = threadIdx.x, g = t>>8, tl = t&255;
  const float* si = src + (size_t)i*12288;
  float* di = dst + (size_t)i*12288;
  if (i < s) {
    for (int idx = t; idx < 12288; idx += 1024) di[idx] = si[idx];
    return;
  }
  const float* sj = src + (size_t)(i-s)*12288;
  if (g == 0)      mmNN<64>(tl, di, 64, si, 64, sj, 64);                   // E' = E2 E1
  else if (g == 1) mmNN<64>(tl, t1, LD, si, 64, sj+4096, 64);              // E2 W1
  else if (g == 2) mmNN<64>(tl, t2, LD, si+4096, 64, sj+8192, 64);         // W2 F1
  else             mmNN<64>(tl, di+8192, 64, si+8192, 64, sj+8192, 64);    // F' = F2 F1
  __syncthreads();
  for (int idx = t; idx < 4096; idx += 1024) {
    const int p = (idx>>6)*LD + (idx&63);
    di[4096+idx] = t1[p] + t2[p];
  }
}

__global__ __launch_bounds__(256) void k_sb2(const float* __restrict__ phi, const float* __restrict__ P0, float* __restrict__ ws)
{ // KF boundary states: SB[c] = Phi_{c-1} @ [I; P0]
  const int c = blockIdx.x, t = threadIdx.x;
  float* D = ws + OFF_SB2 + (size_t)c*8192;
  if (c == 0) {
    for (int idx = t; idx < 4096; idx += 256) {
      const int r = idx>>6, cc = idx&63;
      D[idx] = (r==cc)?1.f:0.f;
      D[4096+idx] = P0[idx];
    }
    return;
  }
  const float* ph = phi + (size_t)(c-1)*12288;
  mmNN<64>(t, D, 64, ph+4096, 64, P0, 64, ph, 64);    // U = W@P0 + E
  mmNN<64>(t, D+4096, 64, ph+8192, 64, P0, 64);       // V = F@P0
}

__global__ __launch_bounds__(1024) void k_uvwalk(const float* __restrict__ ws_aeff, const float* __restrict__ ws_qp,
    const float* __restrict__ ws_sb2, float* __restrict__ ws_uv)
{
  __shared__ float U[64*LD], V[64*LD], T1[64*LD], T2[64*LD], T3[64*LD];
  const int c = blockIdx.x, t = threadIdx.x, g = t>>8, tl = t&255;
  const float* S = ws_sb2 + (size_t)c*8192;
  for (int idx = t; idx < 4096; idx += 1024) {
    const int p = (idx>>6)*LD + (idx&63);
    U[p] = S[idx]; V[p] = S[4096+idx];
  }
  __syncthreads();
  for (int s = 0; s < CHUNK; ++s) {
    const size_t tt = (size_t)c*CHUNK + s;
    const float* Ae = ws_aeff + tt*4096;
    if (g == 0)      mmNN<64>(tl, T1, LD, Ae, 64, U, LD);
    else if (g == 1) mmNN<64>(tl, T2, LD, ws_qp, 64, V, LD);
    else if (g == 2) mmTA<64>(tl, T3, LD, Ae, 64, V, LD);
    __syncthreads();
    float* O = ws_uv + tt*8192;
    for (int idx = t; idx < 4096; idx += 1024) {
      const int p = (idx>>6)*LD + (idx&63);
      const float un = U[p] + DT_C*(T1[p] + T2[p]);
      const float vn = V[p] - DT_C*T3[p];
      U[p] = un; V[p] = vn;
      O[idx] = un; O[4096+idx] = vn;
    }
    __syncthreads();
  }
}

__global__ __launch_bounds__(256) void k_kfper(const float* __restrict__ Cin, const float* __restrict__ outyn, float* __restrict__ ws)
{ // per-t: P_pred, S_inv, Kg, G, b_t
  __shared__ float b1[64*LD], b2[64*LD], b3[64*LD];
  const int t = threadIdx.x, tt = blockIdx.x;
  float* base = ws + OFF_UV + (size_t)tt*8192;
  // stage U->b1 and prefetch V->b3 (overlapped loads), I->b2
  for (int idx = t; idx < 4096; idx += 256) {
    const int r = idx>>6, c = idx&63;
    b1[r*LD+c] = base[idx];             // U
    b3[r*LD+c] = base[4096+idx];        // V (prefetch)
    b2[r*LD+c] = (r==c)?1.f:0.f;
  }
  gjb8(t, b1, b2);                      // b2 = U^{-1}; b1 destroyed
  mmNN<64>(t, b1, LD, b3, LD, b2, LD);  // b1 = X = V @ Uinv
  __syncthreads();
  symTile(t, b3, b1);                   // b3 = P_pred = sym(X)
  __syncthreads();
  mmNN<64>(t, b1, LD, Cin, 64, b3, LD);           // b1 = CtP = C @ P
  __syncthreads();
  mmTB<64>(t, b2, LD, b1, LD, Cin, 64, ws+OFF_VM, 64); // b2 = Sm = CtP C^T + V
  __syncthreads();
  if (t < 64) b2[t*LD+t] += EPS_C;
  for (int idx = t; idx < 4096; idx += 256) {
    const int r = idx>>6, c = idx&63;
    b3[r*LD+c] = (r==c)?1.f:0.f;
  }
  gjb8(t, b2, b3);                      // b3 = S_inv; b2 destroyed
  for (int idx = t; idx < 4096; idx += 256) base[4096+idx] = b3[(idx>>6)*LD+(idx&63)];   // store S_inv
  mmTA<64>(t, b2, LD, b1, LD, b3, LD);  // b2 = Kg = CtP^T @ S_inv
  __syncthreads();
  for (int idx = t; idx < 4096; idx += 256) base[idx] = b2[(idx>>6)*LD+(idx&63)];        // store Kg
  mmNN<64>(t, b3, LD, b2, LD, Cin, 64); // b3 = Z = Kg @ C
  __syncthreads();
  // G = Y + DT*Aeff^T@Y, Y = I - Z^T  -> staged in b1 (LDS), then linear store
  const float* Ae = ws + OFF_AEFF + (size_t)tt*4096;
  float* Gg = ws + OFF_G + (size_t)tt*4096;
  {
    const int r0 = (t>>4)<<2, cg0 = (t&15)<<2;
    float acc[4][4] = {};
    for (int k = 0; k < 64; k += 4) {
      float a_[4][4];   // a_[kk][i] = Aeff[(k+kk)][r0+i]
      #pragma unroll
      for (int kk = 0; kk < 4; ++kk) {
        const float4 x = *(const float4*)&Ae[(k+kk)*64 + r0];
        a_[kk][0]=x.x; a_[kk][1]=x.y; a_[kk][2]=x.z; a_[kk][3]=x.w;
      }
      float yv[4][4];   // yv[j][kk] = Y[k+kk][cg0+j]
      #pragma unroll
      for (int j = 0; j < 4; ++j) {
        const float4 z4 = *(const float4*)&b3[(cg0+j)*LD + k];
        yv[j][0] = -z4.x; yv[j][1] = -z4.y; yv[j][2] = -z4.z; yv[j][3] = -z4.w;
        const int dk = (cg0+j) - k;
        if (dk >= 0 && dk < 4) yv[j][dk] += 1.0f;
      }
      #pragma unroll
      for (int kk = 0; kk < 4; ++kk)
        #pragma unroll
        for (int i = 0; i < 4; ++i) {
          const float a = a_[kk][i];
          #pragma unroll
          for (int j = 0; j < 4; ++j) acc[i][j] += a * yv[j][kk];
        }
    }
    #pragma unroll
    for (int i = 0; i < 4; ++i)
      #pragma unroll
      for (int j = 0; j < 4; ++j) {
        const int rw = r0+i, cw = cg0+j;
        const float Yij = ((rw==cw)?1.f:0.f) - b3[cw*LD + rw];
        b1[rw*LD+cw] = Yij + DT_C*acc[i][j];
      }
  }
  __syncthreads();
  // linear coalesced G store (b1 -> global)
  for (int idx = t; idx < 4096; idx += 256) Gg[idx] = b1[(idx>>6)*LD+(idx&63)];
  // fused b_t = yn_t @ Kg^T  (Kg live in b2; yn streamed from global) -> staged in b3
  mm32TB<64>(t, b3, LD, outyn + (size_t)tt*64, (size_t)131072, b2, LD);
  __syncthreads();
  float* Bout = ws + OFF_B + (size_t)tt*2048;
  for (int idx = t; idx < 2048; idx += 256) Bout[idx] = b3[(idx>>6)*LD+(idx&63)];
}

__global__ __launch_bounds__(1024) void k_ops3(const float* __restrict__ ws_g, const float* __restrict__ ws_b,
    float* __restrict__ dG, float* __restrict__ dB)
{ // per-chunk x-op product (G, b)
  __shared__ float Gc[64*LD], TG[64*LD], bc[NB*LD], Tb[NB*LD];
  const int t = threadIdx.x, c = blockIdx.x, g = t >> 8, tl = t & 255;
  for (int idx = t; idx < 4096; idx += 1024) {
    const int r = idx>>6, cc = idx&63;
    Gc[r*LD+cc] = (r==cc)?1.f:0.f;
  }
  for (int idx = t; idx < 2048; idx += 1024) bc[(idx>>6)*LD+(idx&63)] = 0.f;
  __syncthreads();
  for (int s = 0; s < CHUNK; ++s) {
    const size_t tt = (size_t)c*CHUNK + s;
    const float* Gt = ws_g + tt*4096;
    if (g == 0)      mmNN<64>(tl, TG, LD, Gc, LD, Gt, 64);
    else if (g == 1) mm32NN<64>(tl, Tb, LD, bc, LD, Gt, 64);
    __syncthreads();
    for (int idx = t; idx < 4096; idx += 1024) {
      const int p = (idx>>6)*LD + (idx&63);
      Gc[p] = TG[p];
    }
    const float* bt = ws_b + tt*2048;
    for (int idx = t; idx < 2048; idx += 1024) {
      const int p = (idx>>6)*LD + (idx&63);
      bc[p] = Tb[p] + bt[idx];
    }
    __syncthreads();
  }
  for (int idx = t; idx < 4096; idx += 1024) dG[(size_t)c*4096 + idx] = Gc[(idx>>6)*LD+(idx&63)];
  for (int idx = t; idx < 2048; idx += 1024) dB[(size_t)c*2048 + idx] = bc[(idx>>6)*LD+(idx&63)];
}

__global__ __launch_bounds__(512) void k_scan3(const float* __restrict__ sG, const float* __restrict__ sB,
    float* __restrict__ dG, float* __restrict__ dB, int s)
{
  const int i = blockIdx.x, t = threadIdx.x, g = t>>8, tl = t&255;
  if (i < s) {
    for (int idx = t; idx < 4096; idx += 512) dG[(size_t)i*4096+idx] = sG[(size_t)i*4096+idx];
    for (int idx = t; idx < 2048; idx += 512) dB[(size_t)i*2048+idx] = sB[(size_t)i*2048+idx];
    return;
  }
  const float* Ge = sG + (size_t)(i-s)*4096;  // earlier
  const float* Gl = sG + (size_t)i*4096;      // later
  if (g == 0) mmNN<64>(tl, dG + (size_t)i*4096, 64, Ge, 64, Gl, 64);                             // G' = Ge @ Gl
  else        mm32NN<64>(tl, dB + (size_t)i*2048, 64, sB + (size_t)(i-s)*2048, 64, Gl, 64,
                         sB + (size_t)i*2048, 64);                                               // b' = be@Gl + bl
}

__global__ __launch_bounds__(256) void k_xb(const float* __restrict__ phiG, const float* __restrict__ phiB,
    const float* __restrict__ x0, float* __restrict__ ws)
{
  __shared__ float v[64];
  const int c = blockIdx.x, t = threadIdx.x;
  float* D = ws + OFF_XB + (size_t)c*2048;
  if (c == 0) {
    for (int idx = t; idx < 2048; idx += 256) D[idx] = x0[idx&63];
    return;
  }
  const float* G = phiG + (size_t)(c-1)*4096;
  const float* b = phiB + (size_t)(c-1)*2048;
  if (t < 64) {
    float acc = 0.f;
    for (int k = 0; k < 64; ++k) acc += x0[k]*G[k*64 + t];
    v[t] = acc;
  }
  __syncthreads();
  for (int idx = t; idx < 2048; idx += 256) D[idx] = v[idx&63] + b[idx];
}

__global__ __launch_bounds__(256) void k_xwalk(const float* __restrict__ ws_g, const float* __restrict__ ws_b,
    const float* __restrict__ ws_xb, float* __restrict__ outx)
{
  __shared__ float x[NB*LD], xn[NB*LD];
  const int c = blockIdx.x, t = threadIdx.x;
  const float* X0 = ws_xb + (size_t)c*2048;
  for (int idx = t; idx < 2048; idx += 256) x[(idx>>6)*LD+(idx&63)] = X0[idx];
  __syncthreads();
  for (int s = 0; s < CHUNK; ++s) {
    const size_t tt = (size_t)c*CHUNK + s;
    mm32NN<64>(t, xn, LD, x, LD, ws_g + tt*4096, 64, ws_b + tt*2048, 64);
    __syncthreads();
    for (int idx = t; idx < 2048; idx += 256) {
      const int i = idx>>6, d = idx&63;
      const float val = xn[i*LD+d];
      x[i*LD+d] = val;
      outx[(size_t)i*131072 + tt*64 + d] = val;
    }
    __syncthreads();
  }
}

__global__ __launch_bounds__(256) void k_final(const float* __restrict__ Cin, const float* __restrict__ x0,
    const float* __restrict__ outx, const float* __restrict__ outyn,
    float* __restrict__ outu, float* __restrict__ outyp, float* __restrict__ ws)
{
  __shared__ float xc[NB*LD], z[NB*LD], t1[NB*LD], t2[NB*LD];
  __shared__ float red4[4];
  const int tt = blockIdx.x, t = threadIdx.x;
  for (int idx = t; idx < 2048; idx += 256) {
    const int i = idx>>6, d = idx&63;
    xc[i*LD+d] = outx[(size_t)i*131072 + (size_t)tt*64 + d];
    z[i*LD+d]  = (tt == 0) ? x0[d] : outx[(size_t)i*131072 + (size_t)(tt-1)*64 + d];
  }
  __syncthreads();
  mm32TB<64>(t, t1, LD, xc, LD, ws + OFF_K + (size_t)tt*4096, 64, nullptr, 0, -1.0f);  // u
  mm32TB<64>(t, t2, LD, xc, LD, Cin, 64);                                              // y_pred
  __syncthreads();
  for (int idx = t; idx < 2048; idx += 256) {
    const int i = idx>>6, d = idx&63;
    outu[(size_t)i*131072 + (size_t)tt*64 + d]  = t1[i*LD+d];
    outyp[(size_t)i*131072 + (size_t)tt*64 + d] = t2[i*LD+d];
  }
  __syncthreads();
  mm32NN<64>(t, t2, LD, xc, LD, ws + OFF_Q, 64);     // x @ Q
  __syncthreads();
  const int i_ = t >> 3, lane8 = t & 7;
  float cpart = 0.f;
  for (int d = lane8; d < 64; d += 8) cpart += t2[i_*LD+d]*xc[i_*LD+d];
  __syncthreads();
  mm32NN<64>(t, t2, LD, t1, LD, ws + OFF_R, 64);     // u @ R
  __syncthreads();
  for (int d = lane8; d < 64; d += 8) cpart += t2[i_*LD+d]*t1[i_*LD+d];
  cpart += __shfl_down(cpart, 4, 8);
  cpart += __shfl_down(cpart, 2, 8);
  cpart += __shfl_down(cpart, 1, 8);
  if (lane8 == 0) ws[OFF_COST + (size_t)tt*32 + i_] = cpart;
  __syncthreads();
  mm32TB<64>(t, t2, LD, z, LD, ws + OFF_AEFF + (size_t)tt*4096, 64, z, LD, DT_C);      // x_pred
  __syncthreads();
  mm32TB<64>(t, t1, LD, t2, LD, Cin, 64, outyn + (size_t)tt*64, (size_t)131072, -1.0f);// resid = yn - x_pred C^T
  __syncthreads();
  mm32TB<64>(t, z, LD, t1, LD, ws + OFF_UV + (size_t)tt*8192 + 4096, 64);              // w = resid @ S_inv^T
  __syncthreads();
  float q = 0.f;
  for (int idx = t; idx < 2048; idx += 256) {
    const int p = (idx>>6)*LD + (idx&63);
    q += t1[p]*z[p];
  }
  q += __shfl_down(q, 32); q += __shfl_down(q, 16); q += __shfl_down(q, 8);
  q += __shfl_down(q, 4);  q += __shfl_down(q, 2);  q += __shfl_down(q, 1);
  if ((t & 63) == 0) red4[t>>6] = q;
  __syncthreads();
  if (t == 0) ws[OFF_QUAD + tt] = red4[0]+red4[1]+red4[2]+red4[3];
}

__global__ __launch_bounds__(256) void k_scalars(const float* __restrict__ ws, float* __restrict__ out)
{
  __shared__ float red[256];
  const int t = threadIdx.x;
  float q = 0.f;
  for (int i = t; i < 2048; i += 256) q += ws[OFF_QUAD + i];
  red[t] = q;
  __syncthreads();
  for (int s = 128; s > 0; s >>= 1) { if (t < s) red[t] += red[t+s]; __syncthreads(); }
  const float quadsum = red[0];
  __syncthreads();
  {
    const int b = t & 31, chunk = t >> 5;
    float a = 0.f;
    for (int j = 0; j < 256; ++j) a += ws[OFF_COST + (size_t)(chunk*256 + j)*32 + b];
    red[t] = a;
  }
  __syncthreads();
  if (t < 32) {
    float a = 0.f;
    for (int ch = 0; ch < 8; ++ch) a += red[ch*32 + t];
    red[t] = a;
  }
  __syncthreads();
  if (t == 0) {
    float cc = 0.f;
    for (int b = 0; b < 32; ++b) cc += red[b];
    out[1] = cc / 32.0f;
    const float ld = ws[OFF_LOGDET];
    out[0] = -0.5f*(quadsum + 2048.0f*(ld + 64.0f*LOG2PI)) / 2048.0f;
  }
}

// =====================================================================
extern "C" void kernel_launch(void* const* d_in, const int* in_sizes, int n_in,
                              void* d_out, int out_size, void* d_ws, size_t ws_size,
                              hipStream_t stream)
{
  (void)in_sizes; (void)n_in; (void)out_size; (void)ws_size;
  const float* y   = (const float*)d_in[0];
  const float* A   = (const float*)d_in[1];
  const float* Bi  = (const float*)d_in[2];
  const float* C   = (const float*)d_in[3];
  const float* LQ  = (const float*)d_in[4];
  const float* LR  = (const float*)d_in[5];
  const float* LV  = (const float*)d_in[6];
  const float* LQp = (const float*)d_in[7];
  const float* x0  = (const float*)d_in[8];
  const float* P0  = (const float*)d_in[9];
  float* out = (float*)d_out;
  float* ws  = (float*)d_ws;

  k_stats<<<256, 256, 0, stream>>>(y, ws);
  k_setup<<<1, 256, 0, stream>>>(A, Bi, LQ, LR, LV, LQp, ws);
  k_yn<<<4096, 256, 0, stream>>>(y, ws, out);

  // chain[j] = M^(2^j), j = 1..11 (single launch, LDS double-buffered)
  k_sqchain<<<1, 1024, 0, stream>>>(ws + OFF_CHAIN);
  // fused power table (M^0..M^63) + boundary states SB_k = M^(64k) S0
  for (int j = 0; j <= 5; ++j)
    k_powbounds<<<6 << j, 256, 0, stream>>>(ws + OFF_CHAIN, ws, j);

  k_lqr<<<2048, 256, 0, stream>>>(A, Bi, ws);

  // KF covariance operator scan (OPS2 ping-pong aliased into the UV region,
  // which is dead until k_uvwalk writes it)
  k_ops2<<<NCH, 1024, 0, stream>>>(ws + OFF_AEFF, ws + OFF_QP, ws + OFF_OPS2);
  {
    float* pa = ws + OFF_OPS2;
    float* pb = pa + (size_t)NCH*12288;
    float* src = pa; float* dst = pb;
    for (int s = 1; s < NCH; s <<= 1) {
      k_scan2<<<NCH, 1024, 0, stream>>>(src, dst, s);
      float* tmp = src; src = dst; dst = tmp;
    }
    k_sb2<<<NCH, 256, 0, stream>>>(src, P0, ws);
  }
  k_uvwalk<<<NCH, 1024, 0, stream>>>(ws + OFF_AEFF, ws + OFF_QP, ws + OFF_SB2, ws + OFF_UV);
  k_kfper<<<2048, 256, 0, stream>>>(C, out + OOFF_YN, ws);

  // x-filter affine scan
  k_ops3<<<NCH, 1024, 0, stream>>>(ws + OFF_G, ws + OFF_B, ws + OFF_OPS3G, ws + OFF_OPS3B);
  {
    float* ga = ws + OFF_OPS3G; float* gb = ga + (size_t)NCH*4096;
    float* ba = ws + OFF_OPS3B; float* bb = ba + (size_t)NCH*2048;
    float *gs = ga, *gd = gb, *bs = ba, *bd = bb;
    for (int s = 1; s < NCH; s <<= 1) {
      k_scan3<<<NCH, 512, 0, stream>>>(gs, bs, gd, bd, s);
      float* t1p = gs; gs = gd; gd = t1p;
      float* t2p = bs; bs = bd; bd = t2p;
    }
    k_xb<<<NCH, 256, 0, stream>>>(gs, bs, x0, ws);
  }
  k_xwalk<<<NCH, 256, 0, stream>>>(ws + OFF_G, ws + OFF_B, ws + OFF_XB, out + OOFF_XF);

  // epilogue
  k_final<<<2048, 256, 0, stream>>>(C, x0, out + OOFF_XF, out + OOFF_YN, out + OOFF_U, out + OOFF_YP, ws);
  k_scalars<<<1, 256, 0, stream>>>(ws, out);
}

// Round 15
// 2307.269 us; speedup vs baseline: 1.0658x; 1.0658x over previous
//
#include <hip/hip_runtime.h>
#include <math.h>

#define XD 64
#define SEQL 2048
#define NB 32
#define DT_C  (1.0f/1024.0f)
#define EPS_C 1e-4f
#define LD 68
#define LOG2PI 1.8378770664093453f
#define CHUNK 8
#define NCH 256

// ---------------- workspace offsets (floats) ----------------
#define OFF_PARTIAL 0u
#define OFF_MEAN    32768u
#define OFF_STD     32832u
#define OFF_Q       32896u
#define OFF_R       36992u
#define OFF_VM      41088u
#define OFF_QP      45184u
#define OFF_RIREG   49280u
#define OFF_LOGDET  53376u
#define OFF_CHAIN   53440u                      /* 12*16384 */
#define OFF_POW     250048u                     /* 64*16384 */
#define OFF_BOUNDS  1298624u                    /* 33*8192 */
#define OFF_K       1568960u                    /* 2048*4096 */
#define OFF_AEFF    9957568u                    /* 2048*4096 */
#define OFF_UV      18346176u                   /* 2048*8192 ; Kg/Sinv overlay; OPS2 aliases here pre-uvwalk */
#define OFF_G       35123392u                   /* 2048*4096 */
#define OFF_B       43512000u                   /* 2048*2048 */
#define OFF_OPS2    OFF_UV                      /* 2*256*12288 aliased into UV (dead until uvwalk) */
#define OFF_OPS3G   47706304u                   /* 2*256*4096 */
#define OFF_OPS3B   49803456u                   /* 2*256*2048 */
#define OFF_SB2     50852032u                   /* 256*8192 */
#define OFF_XB      52949184u                   /* 256*2048 */
#define OFF_QUAD    53473472u                   /* 2048 */
#define OFF_COST    53475520u                   /* 2048*32 */
#define OFF_BRI     53541056u                   /* 4096 : B @ inv(R+eps I) */

// ---------------- output offsets (floats) ----------------
#define OOFF_XF 2
#define OOFF_U  4194306
#define OOFF_YP 8388610
#define OOFF_YN 12582914

// =====================================================================
// 64x64 matmul helpers: 256 threads, 16 outputs/thread (4x4 tile).
// out = alpha*(op(A)@op(B)) [+ addC]
// =====================================================================
template<int KD>
__device__ __forceinline__ void mmNN(int t, float* __restrict__ out, int ldo,
    const float* __restrict__ A, int lda, const float* __restrict__ B, int ldb,
    const float* __restrict__ addC = nullptr, int ldc = 0, float alpha = 1.0f)
{
  const int r0 = (t >> 4) << 2, c0 = (t & 15) << 2;
  float acc[4][4] = {};
  for (int k = 0; k < KD; k += 4) {
    float a_[4][4];
    #pragma unroll
    for (int i = 0; i < 4; ++i) {
      const float4 x = *(const float4*)&A[(r0+i)*lda + k];
      a_[i][0]=x.x; a_[i][1]=x.y; a_[i][2]=x.z; a_[i][3]=x.w;
    }
    #pragma unroll
    for (int kk = 0; kk < 4; ++kk) {
      const float4 bv = *(const float4*)&B[(k+kk)*ldb + c0];
      #pragma unroll
      for (int i = 0; i < 4; ++i) {
        const float a = a_[i][kk];
        acc[i][0] += a*bv.x; acc[i][1] += a*bv.y; acc[i][2] += a*bv.z; acc[i][3] += a*bv.w;
      }
    }
  }
  #pragma unroll
  for (int i = 0; i < 4; ++i)
    #pragma unroll
    for (int j = 0; j < 4; ++j) {
      float v = alpha*acc[i][j];
      if (addC) v += addC[(r0+i)*ldc + (c0+j)];
      out[(r0+i)*ldo + (c0+j)] = v;
    }
}

template<int KD>
__device__ __forceinline__ void mmTA(int t, float* __restrict__ out, int ldo,
    const float* __restrict__ A, int lda, const float* __restrict__ B, int ldb,
    const float* __restrict__ addC = nullptr, int ldc = 0, float alpha = 1.0f)
{ // out = A^T @ B  (A is KD x 64)
  const int r0 = (t >> 4) << 2, c0 = (t & 15) << 2;
  float acc[4][4] = {};
  for (int k = 0; k < KD; k += 4) {
    #pragma unroll
    for (int kk = 0; kk < 4; ++kk) {
      const float4 av4 = *(const float4*)&A[(k+kk)*lda + r0];
      const float4 bv4 = *(const float4*)&B[(k+kk)*ldb + c0];
      const float av[4] = {av4.x, av4.y, av4.z, av4.w};
      const float bv[4] = {bv4.x, bv4.y, bv4.z, bv4.w};
      #pragma unroll
      for (int i = 0; i < 4; ++i)
        #pragma unroll
        for (int j = 0; j < 4; ++j)
          acc[i][j] += av[i]*bv[j];
    }
  }
  #pragma unroll
  for (int i = 0; i < 4; ++i)
    #pragma unroll
    for (int j = 0; j < 4; ++j) {
      float v = alpha*acc[i][j];
      if (addC) v += addC[(r0+i)*ldc + (c0+j)];
      out[(r0+i)*ldo + (c0+j)] = v;
    }
}

template<int KD>
__device__ __forceinline__ void mmTB(int t, float* __restrict__ out, int ldo,
    const float* __restrict__ A, int lda, const float* __restrict__ B, int ldb,
    const float* __restrict__ addC = nullptr, int ldc = 0, float alpha = 1.0f)
{ // out = A @ B^T  (B is 64 x KD)
  const int r0 = (t >> 4) << 2, c0 = (t & 15) << 2;
  float acc[4][4] = {};
  for (int k = 0; k < KD; k += 4) {
    float a_[4][4], b_[4][4];
    #pragma unroll
    for (int i = 0; i < 4; ++i) {
      const float4 x = *(const float4*)&A[(r0+i)*lda + k];
      a_[i][0]=x.x; a_[i][1]=x.y; a_[i][2]=x.z; a_[i][3]=x.w;
    }
    #pragma unroll
    for (int j = 0; j < 4; ++j) {
      const float4 x = *(const float4*)&B[(c0+j)*ldb + k];
      b_[j][0]=x.x; b_[j][1]=x.y; b_[j][2]=x.z; b_[j][3]=x.w;
    }
    #pragma unroll
    for (int i = 0; i < 4; ++i)
      #pragma unroll
      for (int j = 0; j < 4; ++j)
        acc[i][j] += a_[i][0]*b_[j][0] + a_[i][1]*b_[j][1] + a_[i][2]*b_[j][2] + a_[i][3]*b_[j][3];
  }
  #pragma unroll
  for (int i = 0; i < 4; ++i)
    #pragma unroll
    for (int j = 0; j < 4; ++j) {
      float v = alpha*acc[i][j];
      if (addC) v += addC[(r0+i)*ldc + (c0+j)];
      out[(r0+i)*ldo + (c0+j)] = v;
    }
}

// b_out = 0.5*(X + X^T) tile-based (4x4 tiles, float4 row-major accesses).
__device__ __forceinline__ void symTile(int t, float* __restrict__ outb, const float* __restrict__ X)
{
  const int r0 = (t >> 4) << 2, c0 = (t & 15) << 2;
  float xa[4][4], xb[4][4];
  #pragma unroll
  for (int i = 0; i < 4; ++i) {
    const float4 u = *(const float4*)&X[(r0+i)*LD + c0];
    xa[i][0]=u.x; xa[i][1]=u.y; xa[i][2]=u.z; xa[i][3]=u.w;
    const float4 v = *(const float4*)&X[(c0+i)*LD + r0];
    xb[i][0]=v.x; xb[i][1]=v.y; xb[i][2]=v.z; xb[i][3]=v.w;
  }
  #pragma unroll
  for (int i = 0; i < 4; ++i) {
    float4 o;
    o.x = 0.5f*(xa[i][0] + xb[0][i]);
    o.y = 0.5f*(xa[i][1] + xb[1][i]);
    o.z = 0.5f*(xa[i][2] + xb[2][i]);
    o.w = 0.5f*(xa[i][3] + xb[3][i]);
    *(float4*)&outb[(r0+i)*LD + c0] = o;
  }
}

// 32x64 = (32xKD)@(KDx64) variants: 256 threads, 8 outputs (2x4 tile)
template<int KD>
__device__ __forceinline__ void mm32NN(int t, float* __restrict__ out, int ldo,
    const float* __restrict__ A, int lda, const float* __restrict__ B, int ldb,
    const float* __restrict__ addC = nullptr, int ldc = 0, float alpha = 1.0f)
{
  const int r0 = (t >> 4) << 1, c0 = (t & 15) << 2;
  float acc[2][4] = {};
  for (int k = 0; k < KD; k += 4) {
    float a_[2][4];
    #pragma unroll
    for (int i = 0; i < 2; ++i) {
      const float4 x = *(const float4*)&A[(r0+i)*lda + k];
      a_[i][0]=x.x; a_[i][1]=x.y; a_[i][2]=x.z; a_[i][3]=x.w;
    }
    #pragma unroll
    for (int kk = 0; kk < 4; ++kk) {
      const float4 bv = *(const float4*)&B[(k+kk)*ldb + c0];
      #pragma unroll
      for (int i = 0; i < 2; ++i) {
        const float a = a_[i][kk];
        acc[i][0] += a*bv.x; acc[i][1] += a*bv.y; acc[i][2] += a*bv.z; acc[i][3] += a*bv.w;
      }
    }
  }
  #pragma unroll
  for (int i = 0; i < 2; ++i)
    #pragma unroll
    for (int j = 0; j < 4; ++j) {
      float v = alpha*acc[i][j];
      if (addC) v += addC[(r0+i)*ldc + (c0+j)];
      out[(r0+i)*ldo + (c0+j)] = v;
    }
}

template<int KD>
__device__ __forceinline__ void mm32TB(int t, float* __restrict__ out, int ldo,
    const float* __restrict__ A, size_t lda, const float* __restrict__ B, int ldb,
    const float* __restrict__ addC = nullptr, size_t ldc = 0, float alpha = 1.0f)
{ // out = A @ B^T
  const int r0 = (t >> 4) << 1, c0 = (t & 15) << 2;
  float acc[2][4] = {};
  for (int k = 0; k < KD; k += 4) {
    float a_[2][4], b_[4][4];
    #pragma unroll
    for (int i = 0; i < 2; ++i) {
      const float4 x = *(const float4*)&A[(size_t)(r0+i)*lda + k];
      a_[i][0]=x.x; a_[i][1]=x.y; a_[i][2]=x.z; a_[i][3]=x.w;
    }
    #pragma unroll
    for (int j = 0; j < 4; ++j) {
      const float4 x = *(const float4*)&B[(c0+j)*ldb + k];
      b_[j][0]=x.x; b_[j][1]=x.y; b_[j][2]=x.z; b_[j][3]=x.w;
    }
    #pragma unroll
    for (int i = 0; i < 2; ++i)
      #pragma unroll
      for (int j = 0; j < 4; ++j)
        acc[i][j] += a_[i][0]*b_[j][0] + a_[i][1]*b_[j][1] + a_[i][2]*b_[j][2] + a_[i][3]*b_[j][3];
  }
  #pragma unroll
  for (int i = 0; i < 2; ++i)
    #pragma unroll
    for (int j = 0; j < 4; ++j) {
      float v = alpha*acc[i][j];
      if (addC) v += addC[(size_t)(r0+i)*ldc + (c0+j)];
      out[(r0+i)*ldo + (c0+j)] = v;
    }
}

// Gauss-Jordan (no pivoting): RHS <- Am^{-1} RHS ; destroys Am. 256 threads.
// Used only in the single-block k_setup (cost negligible).
__device__ __forceinline__ void gj64(int t, float* __restrict__ Am, float* __restrict__ R)
{
  const int r = t >> 2;
  const int c0 = (t & 3) << 4;
  for (int k = 0; k < 64; ++k) {
    __syncthreads();
    const float pv = Am[k*LD + k];
    const float f = Am[r*LD + k] / pv;
    if (r != k) {
      #pragma unroll
      for (int c = 0; c < 16; c += 4) {
        float4 ak = *(const float4*)&Am[k*LD + c0 + c];
        float4 ar = *(float4*)&Am[r*LD + c0 + c];
        ar.x -= f*ak.x; ar.y -= f*ak.y; ar.z -= f*ak.z; ar.w -= f*ak.w;
        *(float4*)&Am[r*LD + c0 + c] = ar;
        float4 rk = *(const float4*)&R[k*LD + c0 + c];
        float4 rr = *(float4*)&R[r*LD + c0 + c];
        rr.x -= f*rk.x; rr.y -= f*rk.y; rr.z -= f*rk.z; rr.w -= f*rk.w;
        *(float4*)&R[r*LD + c0 + c] = rr;
      }
    }
  }
  __syncthreads();
  const float dinv = 1.0f / Am[r*LD + r];
  #pragma unroll
  for (int c = 0; c < 16; c += 4) {
    float4 rr = *(float4*)&R[r*LD + c0 + c];
    rr.x *= dinv; rr.y *= dinv; rr.z *= dinv; rr.w *= dinv;
    *(float4*)&R[r*LD + c0 + c] = rr;
  }
  __syncthreads();
}

// =====================================================================
// Blocked Gauss-Jordan, 8x8 pivot blocks, IN-PLACE panel, REDUNDANT
// per-wave diagonal inverse: R <- Am^{-1} R ; destroys Am.
// 256 threads, 3 barriers per block-step. Multiplier loads hoisted to
// block-step start. HW-verified lineage (R10/R11/R12).
// =====================================================================
__device__ __forceinline__ void gjb8(int t, float* __restrict__ Am, float* __restrict__ R)
{
  const int r  = t >> 2;           // row 0..63
  const int c0 = (t & 3) << 4;     // 16-col quadrant
  const int j2 = t >> 5;           // pivot row this thread writes (0..7)
  const int cc = (t & 31) << 2;    // combined col (Am cols 0..63, R cols 64..127)
  const int lane = t & 63;
  const int li = lane >> 3, lj = lane & 7;
  for (int kb = 0; kb < 8; ++kb) {
    const int K = kb << 3;
    __syncthreads();               // prev trailing update complete
    const bool inK = ((unsigned)(r - K)) < 8u;
    float4 f0 = make_float4(0.f,0.f,0.f,0.f), f1 = f0;
    if (!inK) {
      f0 = *(const float4*)&Am[r*LD + K];
      f1 = *(const float4*)&Am[r*LD + K + 4];
    }
    // ---- every wave: W = inv(Am[K..K+7][K..K+7]) in registers ----
    float a = Am[(K+li)*LD + K + lj];
    float w = (li == lj) ? 1.0f : 0.0f;
    #pragma unroll
    for (int p = 0; p < 8; ++p) {
      const float pv  = __shfl(a, p*8 + p, 64);
      const float pvr = __builtin_amdgcn_rcpf(pv);
      const float aip = __shfl(a, li*8 + p, 64);
      const float apj = __shfl(a, p*8 + lj, 64);
      const float wpj = __shfl(w, p*8 + lj, 64);
      const float fi  = aip * pvr;
      if (li == p) { a *= pvr; w *= pvr; }
      else         { a -= fi * apj; w -= fi * wpj; }
    }
    float wrow[8];
    #pragma unroll
    for (int m = 0; m < 8; ++m) wrow[m] = __shfl(w, j2*8 + m, 64);
    // ---- panel = W @ old rows(K..K+7) of [Am | R] into registers ----
    const int c4 = cc & 63;
    float* srcB = (cc < 64) ? Am : R;
    float4 acc = make_float4(0.f, 0.f, 0.f, 0.f);
    #pragma unroll
    for (int m = 0; m < 8; ++m) {
      const float4 rv = *(const float4*)&srcB[(K+m)*LD + c4];
      acc.x += wrow[m]*rv.x; acc.y += wrow[m]*rv.y; acc.z += wrow[m]*rv.z; acc.w += wrow[m]*rv.w;
    }
    __syncthreads();               // all readers done with old pivot rows
    *(float4*)&srcB[(K+j2)*LD + c4] = acc;
    __syncthreads();               // new pivot rows visible
    // ---- rank-8 trailing update (non-pivot rows only) ----
    if (!inK) {
      const float fj[8] = {f0.x, f0.y, f0.z, f0.w, f1.x, f1.y, f1.z, f1.w};
      #pragma unroll
      for (int c = 0; c < 16; c += 4) {
        const int cab = c0 + c;
        if (cab >= K + 8) {
          float4 v = *(float4*)&Am[r*LD + cab];
          #pragma unroll
          for (int j = 0; j < 8; ++j) {
            const float4 p4 = *(const float4*)&Am[(K+j)*LD + cab];
            v.x -= fj[j]*p4.x; v.y -= fj[j]*p4.y; v.z -= fj[j]*p4.z; v.w -= fj[j]*p4.w;
          }
          *(float4*)&Am[r*LD + cab] = v;
        }
      }
      #pragma unroll
      for (int c = 0; c < 16; c += 4) {
        const int cab = c0 + c;
        float4 v = *(float4*)&R[r*LD + cab];
        #pragma unroll
        for (int j = 0; j < 8; ++j) {
          const float4 p4 = *(const float4*)&R[(K+j)*LD + cab];
          v.x -= fj[j]*p4.x; v.y -= fj[j]*p4.y; v.z -= fj[j]*p4.z; v.w -= fj[j]*p4.w;
        }
        *(float4*)&R[r*LD + cab] = v;
      }
    }
  }
  __syncthreads();
}

// =====================================================================
// Kernels
// =====================================================================

__global__ __launch_bounds__(256) void k_stats(const float* __restrict__ y, float* __restrict__ ws)
{
  __shared__ float sbuf[4][128];
  const int t = threadIdx.x, blk = blockIdx.x;
  const int d = t & 63, g = t >> 6;
  float s = 0.f, s2 = 0.f;
  for (int r = g; r < 256; r += 4) {
    const float v = y[(size_t)(blk*256 + r)*64 + d];
    s += v; s2 += v*v;
  }
  sbuf[g][d] = s; sbuf[g][64+d] = s2;
  __syncthreads();
  if (t < 128) ws[OFF_PARTIAL + (size_t)blk*128 + t] = sbuf[0][t]+sbuf[1][t]+sbuf[2][t]+sbuf[3][t];
}

__global__ __launch_bounds__(256) void k_setup(
    const float* __restrict__ A, const float* __restrict__ Bi,
    const float* __restrict__ LQ, const float* __restrict__ LR,
    const float* __restrict__ LV, const float* __restrict__ LQp,
    float* __restrict__ ws)
{
  __shared__ float b1[64*LD], b2[64*LD], b3[64*LD], b4[64*LD], bQ[64*LD];
  __shared__ float sred[128];
  const int t = threadIdx.x;

  if (t < 128) {
    float acc = 0.f;
    for (int p = 0; p < 256; ++p) acc += ws[OFF_PARTIAL + (size_t)p*128 + t];
    sred[t] = acc;
  }
  __syncthreads();
  if (t < 64) {
    const float mean = sred[t] * (1.0f/65536.0f);
    const float var = (sred[64+t] - 65536.0f*mean*mean) * (1.0f/65535.0f);
    ws[OFF_MEAN + t] = mean;
    ws[OFF_STD + t] = sqrtf(var);
  }

  mmTB<64>(t, bQ, LD, LQ, 64, LQ, 64);              // Q
  mmTB<64>(t, b3, LD, LR, 64, LR, 64);              // R
  mmTB<64>(t, ws+OFF_VM, 64, LV, 64, LV, 64);       // V
  mmTB<64>(t, ws+OFF_QP, 64, LQp, 64, LQp, 64);     // Q_proc
  __syncthreads();
  for (int idx = t; idx < 4096; idx += 256) {
    const int r = idx>>6, c = idx&63;
    ws[OFF_Q + idx] = bQ[r*LD+c];
    ws[OFF_R + idx] = b3[r*LD+c];
    b1[r*LD+c] = b3[r*LD+c] + ((r==c)?EPS_C:0.f);
    b2[r*LD+c] = (r==c)?1.f:0.f;
  }
  gj64(t, b1, b2);                                   // b2 = inv(R + eps I)
  mmNN<64>(t, b4, LD, Bi, 64, b2, LD);               // b4 = BRI = B @ inv(R+eps)
  __syncthreads();
  for (int idx = t; idx < 4096; idx += 256) {
    ws[OFF_RIREG + idx] = b2[(idx>>6)*LD+(idx&63)];
    ws[OFF_BRI + idx]   = b4[(idx>>6)*LD+(idx&63)];
  }
  __syncthreads();
  for (int idx = t; idx < 4096; idx += 256) {
    const int r = idx>>6, c = idx&63;
    b1[r*LD+c] = b3[r*LD+c];
    b2[r*LD+c] = (r==c)?1.f:0.f;
  }
  gj64(t, b1, b2);                                   // b2 = inv(R)
  mmTB<64>(t, b3, LD, b2, LD, Bi, 64);               // b3 = Rinv @ B^T
  __syncthreads();
  mmNN<64>(t, b4, LD, Bi, 64, b3, LD);               // b4 = B Rinv B^T
  mmTB<64>(t, b1, LD, LV, 64, LV, 64);               // b1 = V (for logdet)
  __syncthreads();
  if (t < 64) b1[t*LD+t] += EPS_C;
  {
    const int r = t >> 2, c0 = (t & 3) << 4;
    float lsum = 0.f;
    for (int k = 0; k < 64; ++k) {
      __syncthreads();
      const float pv = b1[k*LD+k];
      lsum += logf(pv);
      const float f = b1[r*LD+k] / pv;
      if (r != k) {
        #pragma unroll
        for (int c = 0; c < 16; c += 4) {
          float4 ak = *(const float4*)&b1[k*LD+c0+c];
          float4 ar = *(float4*)&b1[r*LD+c0+c];
          ar.x -= f*ak.x; ar.y -= f*ak.y; ar.z -= f*ak.z; ar.w -= f*ak.w;
          *(float4*)&b1[r*LD+c0+c] = ar;
        }
      }
    }
    if (t == 0) ws[OFF_LOGDET] = lsum;
  }
  __syncthreads();
  // M = I + DT*[[A, -BRB],[-Q, -A^T]]  -> chain[0]
  float* M0 = ws + OFF_CHAIN;
  for (int idx = t; idx < 16384; idx += 256) {
    const int i = idx >> 7, j = idx & 127;
    float v;
    if (i < 64) v = (j < 64) ? (((i==j)?1.f:0.f) + DT_C*A[i*64+j]) : (-DT_C*b4[i*LD + (j-64)]);
    else        v = (j < 64) ? (-DT_C*bQ[(i-64)*LD + j]) : (((i==j)?1.f:0.f) - DT_C*A[(j-64)*64 + (i-64)]);
    M0[idx] = v;
  }
  for (int idx = t; idx < 16384; idx += 256) {
    const int i = idx >> 7, j = idx & 127;
    ws[OFF_POW + idx] = (i==j)?1.f:0.f;              // M^0 = I
  }
  for (int idx = t; idx < 8192; idx += 256) {
    const int i = idx >> 6, j = idx & 63;
    ws[OFF_BOUNDS + idx] = (i < 64) ? ((i==j)?1.f:0.f) : bQ[(i-64)*LD + j];   // S0 = [I; Q]
  }
}

__global__ __launch_bounds__(256) void k_yn(const float* __restrict__ y, const float* __restrict__ ws, float* __restrict__ out)
{
  const size_t i0 = ((size_t)blockIdx.x*256 + threadIdx.x)*4;
  const int d = (int)(i0 & 63);
  const float4 v = *(const float4*)&y[i0];
  const float4 m = *(const float4*)&ws[OFF_MEAN + d];
  const float4 s = *(const float4*)&ws[OFF_STD + d];
  float* o = out + OOFF_YN + i0;
  o[0] = (v.x - m.x)/(s.x + EPS_C);
  o[1] = (v.y - m.y)/(s.y + EPS_C);
  o[2] = (v.z - m.z)/(s.z + EPS_C);
  o[3] = (v.w - m.w)/(s.w + EPS_C);
}

__global__ __launch_bounds__(256) void k_sq(const float* __restrict__ src, float* __restrict__ dst)
{ // dst = src @ src (128x128); grid 16, 8 rows/block
  const int t = threadIdx.x;
  const int r = blockIdx.x*8 + (t >> 5);
  const int c0 = (t & 31) << 2;
  float acc[4] = {0.f,0.f,0.f,0.f};
  for (int k = 0; k < 128; k += 4) {
    const float4 a4 = *(const float4*)&src[r*128 + k];
    const float av[4] = {a4.x, a4.y, a4.z, a4.w};
    #pragma unroll
    for (int kk = 0; kk < 4; ++kk) {
      const float4 bv = *(const float4*)&src[(k+kk)*128 + c0];
      acc[0] += av[kk]*bv.x; acc[1] += av[kk]*bv.y; acc[2] += av[kk]*bv.z; acc[3] += av[kk]*bv.w;
    }
  }
  float4 o; o.x=acc[0]; o.y=acc[1]; o.z=acc[2]; o.w=acc[3];
  *(float4*)&dst[r*128 + c0] = o;
}

__global__ __launch_bounds__(256) void k_powbounds(const float* __restrict__ chain, float* __restrict__ ws, int level)
{ // fused: blocks [0, 4<<level) = pow level; blocks [4<<level, 6<<level) = bounds level
  const int nbp = 4 << level;
  const int t = threadIdx.x;
  if ((int)blockIdx.x < nbp) {
    // ---- pow: powt[i + 2^level] = chain[level] @ powt[i] ----
    const float* chainj = chain + (size_t)level*16384;
    float* powt = ws + OFF_POW;
    const int i = blockIdx.x >> 2, sub = blockIdx.x & 3;
    const float* Bm = powt + (size_t)i*16384;
    float* D = powt + (size_t)(i + (1<<level))*16384;
    const int r0 = sub*32 + ((t >> 4) << 1);
    const int c0 = (t & 15) << 3;
    float acc[2][8] = {};
    for (int k = 0; k < 128; k += 4) {
      float a_[2][4];
      {
        const float4 x = *(const float4*)&chainj[r0*128 + k];
        a_[0][0]=x.x; a_[0][1]=x.y; a_[0][2]=x.z; a_[0][3]=x.w;
        const float4 y2 = *(const float4*)&chainj[(r0+1)*128 + k];
        a_[1][0]=y2.x; a_[1][1]=y2.y; a_[1][2]=y2.z; a_[1][3]=y2.w;
      }
      #pragma unroll
      for (int kk = 0; kk < 4; ++kk) {
        const float4 b0 = *(const float4*)&Bm[(k+kk)*128 + c0];
        const float4 b1v = *(const float4*)&Bm[(k+kk)*128 + c0 + 4];
        #pragma unroll
        for (int i2 = 0; i2 < 2; ++i2) {
          const float a = a_[i2][kk];
          acc[i2][0] += a*b0.x; acc[i2][1] += a*b0.y; acc[i2][2] += a*b0.z; acc[i2][3] += a*b0.w;
          acc[i2][4] += a*b1v.x; acc[i2][5] += a*b1v.y; acc[i2][6] += a*b1v.z; acc[i2][7] += a*b1v.w;
        }
      }
    }
    #pragma unroll
    for (int i2 = 0; i2 < 2; ++i2)
      #pragma unroll
      for (int j = 0; j < 8; ++j)
        D[(r0+i2)*128 + c0 + j] = acc[i2][j];
  } else {
    // ---- bounds: bounds[k + 2^level] = chain[6+level] @ bounds[k] ----
    const int bb = blockIdx.x - nbp;
    const int kb = bb >> 1, sub = bb & 1;
    const int dsti = kb + (1 << level);
    if (dsti > 32) return;
    const float* chainp = chain + (size_t)(6+level)*16384;
    const float* S = ws + OFF_BOUNDS + (size_t)kb*8192;
    float* D = ws + OFF_BOUNDS + (size_t)dsti*8192;
    const int r0 = sub*64 + ((t >> 4) << 2);
    const int c0 = (t & 15) << 2;
    float acc[4][4] = {};
    for (int k = 0; k < 128; k += 4) {
      float a_[4][4];
      #pragma unroll
      for (int i = 0; i < 4; ++i) {
        const float4 x = *(const float4*)&chainp[(r0+i)*128 + k];
        a_[i][0]=x.x; a_[i][1]=x.y; a_[i][2]=x.z; a_[i][3]=x.w;
      }
      #pragma unroll
      for (int kk = 0; kk < 4; ++kk) {
        const float4 bv = *(const float4*)&S[(k+kk)*64 + c0];
        #pragma unroll
        for (int i = 0; i < 4; ++i) {
          const float a = a_[i][kk];
          acc[i][0] += a*bv.x; acc[i][1] += a*bv.y; acc[i][2] += a*bv.z; acc[i][3] += a*bv.w;
        }
      }
    }
    #pragma unroll
    for (int i = 0; i < 4; ++i)
      #pragma unroll
      for (int j = 0; j < 4; ++j)
        D[(r0+i)*64 + c0 + j] = acc[i][j];
  }
}

__global__ __launch_bounds__(256) void k_lqr(const float* __restrict__ Ain, const float* __restrict__ Bin, float* __restrict__ ws)
{ // per-t: S = M^r @ SB_k ; Uinv ; X = V Uinv ; P ; bp ; {K, BRIbp} ; coalesced stores
  __shared__ float b1[64*LD], b2[64*LD], b3[64*LD];
  const int t = threadIdx.x, tt = blockIdx.x;
  const int tp1 = tt + 1, kc = tp1 >> 6, rr = tp1 & 63;
  const float* Mr = ws + OFF_POW + (size_t)rr*16384;
  const float* SB = ws + OFF_BOUNDS + (size_t)kc*8192;
  mmNN<128>(t, b1, LD, Mr, 128, SB, 64);            // U = (Mr@SB)[0:64]
  mmNN<128>(t, b3, LD, Mr + 8192, 128, SB, 64);     // V = (Mr@SB)[64:128]
  for (int idx = t; idx < 4096; idx += 256) {
    const int r = idx>>6, c = idx&63;
    b2[r*LD+c] = (r==c)?1.f:0.f;
  }
  gjb8(t, b1, b2);                                  // b2 = U^{-1}  (leading sync inside)
  mmNN<64>(t, b1, LD, b3, LD, b2, LD);              // b1 = X = V @ Uinv
  __syncthreads();
  symTile(t, b3, b1);                               // b3 = P = sym(X)
  __syncthreads();
  mmTA<64>(t, b1, LD, Bin, 64, b3, LD);             // b1 = bp = B^T P
  __syncthreads();
  mmNN<64>(t, b2, LD, ws+OFF_RIREG, 64, b1, LD);    // b2 = K = RIREG @ bp
  mmNN<64>(t, b3, LD, ws+OFF_BRI, 64, b1, LD);      // b3 = BRI @ bp
  __syncthreads();
  float* Kout = ws + OFF_K + (size_t)tt*4096;
  float* Ae   = ws + OFF_AEFF + (size_t)tt*4096;
  for (int idx = t; idx < 4096; idx += 256) {
    const int p = (idx>>6)*LD + (idx&63);
    Kout[idx] = b2[p];
    Ae[idx]   = Ain[idx] - b3[p];
  }
}

__global__ __launch_bounds__(1024) void k_ops2(const float* __restrict__ ws_aeff, const float* __restrict__ ws_qp, float* __restrict__ dstE)
{ // per-chunk KF transfer-operator product (E,W,F)
  __shared__ float E[64*LD], W[64*LD], F[64*LD], T1[64*LD], T2[64*LD], T3[64*LD], T4[64*LD];
  const int t = threadIdx.x, c = blockIdx.x, g = t >> 8, tl = t & 255;
  for (int idx = t; idx < 4096; idx += 1024) {
    const int r = idx>>6, cc = idx&63; const float id = (r==cc)?1.f:0.f;
    E[r*LD+cc] = id; W[r*LD+cc] = 0.f; F[r*LD+cc] = id;
  }
  __syncthreads();
  for (int s = 0; s < CHUNK; ++s) {
    const float* Ae = ws_aeff + ((size_t)c*CHUNK + s)*4096;
    if (g == 0)      mmNN<64>(tl, T1, LD, Ae, 64, E, LD);
    else if (g == 1) mmNN<64>(tl, T2, LD, Ae, 64, W, LD);
    else if (g == 2) mmNN<64>(tl, T3, LD, ws_qp, 64, F, LD);
    else             mmTA<64>(tl, T4, LD, Ae, 64, F, LD);
    __syncthreads();
    for (int idx = t; idx < 4096; idx += 1024) {
      const int p = (idx>>6)*LD + (idx&63);
      E[p] += DT_C*T1[p];
      W[p] += DT_C*(T2[p] + T3[p]);
      F[p] -= DT_C*T4[p];
    }
    __syncthreads();
  }
  float* dst = dstE + (size_t)c*12288;
  for (int idx = t; idx < 4096; idx += 1024) {
    const int p = (idx>>6)*LD + (idx&63);
    dst[idx] = E[p]; dst[4096+idx] = W[p]; dst[8192+idx] = F[p];
  }
}

__global__ __launch_bounds__(1024) void k_scan2(const float* __restrict__ src, float* __restrict__ dst, int s)
{ // Hillis-Steele compose of (E,W,F) ops; op[i] (later) after op[i-s] (earlier)
  __shared__ float t1[64*LD], t2[64*LD];
  const int i = blockIdx.x, t = threadIdx.x, g = t>>8, tl = t&255;
  const float* si = src + (size_t)i*12288;
  float* di = dst + (size_t)i*12288;
  if (i < s) {
    for (int idx = t; idx < 12288; idx += 1024) di[idx] = si[idx];
    return;
  }
  const float* sj = src + (size_t)(i-s)*12288;
  if (g == 0)      mmNN<64>(tl, di, 64, si, 64, sj, 64);                   // E' = E2 E1
  else if (g == 1) mmNN<64>(tl, t1, LD, si, 64, sj+4096, 64);              // E2 W1
  else if (g == 2) mmNN<64>(tl, t2, LD, si+4096, 64, sj+8192, 64);         // W2 F1
  else             mmNN<64>(tl, di+8192, 64, si+8192, 64, sj+8192, 64);    // F' = F2 F1
  __syncthreads();
  for (int idx = t; idx < 4096; idx += 1024) {
    const int p = (idx>>6)*LD + (idx&63);
    di[4096+idx] = t1[p] + t2[p];
  }
}

__global__ __launch_bounds__(256) void k_sb2(const float* __restrict__ phi, const float* __restrict__ P0, float* __restrict__ ws)
{ // KF boundary states: SB[c] = Phi_{c-1} @ [I; P0]
  const int c = blockIdx.x, t = threadIdx.x;
  float* D = ws + OFF_SB2 + (size_t)c*8192;
  if (c == 0) {
    for (int idx = t; idx < 4096; idx += 256) {
      const int r = idx>>6, cc = idx&63;
      D[idx] = (r==cc)?1.f:0.f;
      D[4096+idx] = P0[idx];
    }
    return;
  }
  const float* ph = phi + (size_t)(c-1)*12288;
  mmNN<64>(t, D, 64, ph+4096, 64, P0, 64, ph, 64);    // U = W@P0 + E
  mmNN<64>(t, D+4096, 64, ph+8192, 64, P0, 64);       // V = F@P0
}

__global__ __launch_bounds__(1024) void k_uvwalk(const float* __restrict__ ws_aeff, const float* __restrict__ ws_qp,
    const float* __restrict__ ws_sb2, float* __restrict__ ws_uv)
{
  __shared__ float U[64*LD], V[64*LD], T1[64*LD], T2[64*LD], T3[64*LD];
  const int c = blockIdx.x, t = threadIdx.x, g = t>>8, tl = t&255;
  const float* S = ws_sb2 + (size_t)c*8192;
  for (int idx = t; idx < 4096; idx += 1024) {
    const int p = (idx>>6)*LD + (idx&63);
    U[p] = S[idx]; V[p] = S[4096+idx];
  }
  __syncthreads();
  for (int s = 0; s < CHUNK; ++s) {
    const size_t tt = (size_t)c*CHUNK + s;
    const float* Ae = ws_aeff + tt*4096;
    if (g == 0)      mmNN<64>(tl, T1, LD, Ae, 64, U, LD);
    else if (g == 1) mmNN<64>(tl, T2, LD, ws_qp, 64, V, LD);
    else if (g == 2) mmTA<64>(tl, T3, LD, Ae, 64, V, LD);
    __syncthreads();
    float* O = ws_uv + tt*8192;
    for (int idx = t; idx < 4096; idx += 1024) {
      const int p = (idx>>6)*LD + (idx&63);
      const float un = U[p] + DT_C*(T1[p] + T2[p]);
      const float vn = V[p] - DT_C*T3[p];
      U[p] = un; V[p] = vn;
      O[idx] = un; O[4096+idx] = vn;
    }
    __syncthreads();
  }
}

__global__ __launch_bounds__(256) void k_kfper(const float* __restrict__ Cin, const float* __restrict__ outyn, float* __restrict__ ws)
{ // per-t: P_pred, S_inv, Kg, G, b_t
  __shared__ float b1[64*LD], b2[64*LD], b3[64*LD];
  const int t = threadIdx.x, tt = blockIdx.x;
  float* base = ws + OFF_UV + (size_t)tt*8192;
  // stage U->b1 and prefetch V->b3 (overlapped loads), I->b2
  for (int idx = t; idx < 4096; idx += 256) {
    const int r = idx>>6, c = idx&63;
    b1[r*LD+c] = base[idx];             // U
    b3[r*LD+c] = base[4096+idx];        // V (prefetch)
    b2[r*LD+c] = (r==c)?1.f:0.f;
  }
  gjb8(t, b1, b2);                      // b2 = U^{-1}; b1 destroyed
  mmNN<64>(t, b1, LD, b3, LD, b2, LD);  // b1 = X = V @ Uinv
  __syncthreads();
  symTile(t, b3, b1);                   // b3 = P_pred = sym(X)
  __syncthreads();
  mmNN<64>(t, b1, LD, Cin, 64, b3, LD);           // b1 = CtP = C @ P
  __syncthreads();
  mmTB<64>(t, b2, LD, b1, LD, Cin, 64, ws+OFF_VM, 64); // b2 = Sm = CtP C^T + V
  __syncthreads();
  if (t < 64) b2[t*LD+t] += EPS_C;
  for (int idx = t; idx < 4096; idx += 256) {
    const int r = idx>>6, c = idx&63;
    b3[r*LD+c] = (r==c)?1.f:0.f;
  }
  gjb8(t, b2, b3);                      // b3 = S_inv; b2 destroyed
  for (int idx = t; idx < 4096; idx += 256) base[4096+idx] = b3[(idx>>6)*LD+(idx&63)];   // store S_inv
  mmTA<64>(t, b2, LD, b1, LD, b3, LD);  // b2 = Kg = CtP^T @ S_inv
  __syncthreads();
  for (int idx = t; idx < 4096; idx += 256) base[idx] = b2[(idx>>6)*LD+(idx&63)];        // store Kg
  mmNN<64>(t, b3, LD, b2, LD, Cin, 64); // b3 = Z = Kg @ C
  __syncthreads();
  // G = Y + DT*Aeff^T@Y, Y = I - Z^T  -> staged in b1 (LDS), then linear store
  const float* Ae = ws + OFF_AEFF + (size_t)tt*4096;
  float* Gg = ws + OFF_G + (size_t)tt*4096;
  {
    const int r0 = (t>>4)<<2, cg0 = (t&15)<<2;
    float acc[4][4] = {};
    for (int k = 0; k < 64; k += 4) {
      float a_[4][4];   // a_[kk][i] = Aeff[(k+kk)][r0+i]
      #pragma unroll
      for (int kk = 0; kk < 4; ++kk) {
        const float4 x = *(const float4*)&Ae[(k+kk)*64 + r0];
        a_[kk][0]=x.x; a_[kk][1]=x.y; a_[kk][2]=x.z; a_[kk][3]=x.w;
      }
      float yv[4][4];   // yv[j][kk] = Y[k+kk][cg0+j]
      #pragma unroll
      for (int j = 0; j < 4; ++j) {
        const float4 z4 = *(const float4*)&b3[(cg0+j)*LD + k];
        yv[j][0] = -z4.x; yv[j][1] = -z4.y; yv[j][2] = -z4.z; yv[j][3] = -z4.w;
        const int dk = (cg0+j) - k;
        if (dk >= 0 && dk < 4) yv[j][dk] += 1.0f;
      }
      #pragma unroll
      for (int kk = 0; kk < 4; ++kk)
        #pragma unroll
        for (int i = 0; i < 4; ++i) {
          const float a = a_[kk][i];
          #pragma unroll
          for (int j = 0; j < 4; ++j) acc[i][j] += a * yv[j][kk];
        }
    }
    #pragma unroll
    for (int i = 0; i < 4; ++i)
      #pragma unroll
      for (int j = 0; j < 4; ++j) {
        const int rw = r0+i, cw = cg0+j;
        const float Yij = ((rw==cw)?1.f:0.f) - b3[cw*LD + rw];
        b1[rw*LD+cw] = Yij + DT_C*acc[i][j];
      }
  }
  __syncthreads();
  // linear coalesced G store (b1 -> global)
  for (int idx = t; idx < 4096; idx += 256) Gg[idx] = b1[(idx>>6)*LD+(idx&63)];
  // fused b_t = yn_t @ Kg^T  (Kg live in b2; yn streamed from global) -> staged in b3
  mm32TB<64>(t, b3, LD, outyn + (size_t)tt*64, (size_t)131072, b2, LD);
  __syncthreads();
  float* Bout = ws + OFF_B + (size_t)tt*2048;
  for (int idx = t; idx < 2048; idx += 256) Bout[idx] = b3[(idx>>6)*LD+(idx&63)];
}

__global__ __launch_bounds__(1024) void k_ops3(const float* __restrict__ ws_g, const float* __restrict__ ws_b,
    float* __restrict__ dG, float* __restrict__ dB)
{ // per-chunk x-op product (G, b)
  __shared__ float Gc[64*LD], TG[64*LD], bc[NB*LD], Tb[NB*LD];
  const int t = threadIdx.x, c = blockIdx.x, g = t >> 8, tl = t & 255;
  for (int idx = t; idx < 4096; idx += 1024) {
    const int r = idx>>6, cc = idx&63;
    Gc[r*LD+cc] = (r==cc)?1.f:0.f;
  }
  for (int idx = t; idx < 2048; idx += 1024) bc[(idx>>6)*LD+(idx&63)] = 0.f;
  __syncthreads();
  for (int s = 0; s < CHUNK; ++s) {
    const size_t tt = (size_t)c*CHUNK + s;
    const float* Gt = ws_g + tt*4096;
    if (g == 0)      mmNN<64>(tl, TG, LD, Gc, LD, Gt, 64);
    else if (g == 1) mm32NN<64>(tl, Tb, LD, bc, LD, Gt, 64);
    __syncthreads();
    for (int idx = t; idx < 4096; idx += 1024) {
      const int p = (idx>>6)*LD + (idx&63);
      Gc[p] = TG[p];
    }
    const float* bt = ws_b + tt*2048;
    for (int idx = t; idx < 2048; idx += 1024) {
      const int p = (idx>>6)*LD + (idx&63);
      bc[p] = Tb[p] + bt[idx];
    }
    __syncthreads();
  }
  for (int idx = t; idx < 4096; idx += 1024) dG[(size_t)c*4096 + idx] = Gc[(idx>>6)*LD+(idx&63)];
  for (int idx = t; idx < 2048; idx += 1024) dB[(size_t)c*2048 + idx] = bc[(idx>>6)*LD+(idx&63)];
}

__global__ __launch_bounds__(512) void k_scan3(const float* __restrict__ sG, const float* __restrict__ sB,
    float* __restrict__ dG, float* __restrict__ dB, int s)
{
  const int i = blockIdx.x, t = threadIdx.x, g = t>>8, tl = t&255;
  if (i < s) {
    for (int idx = t; idx < 4096; idx += 512) dG[(size_t)i*4096+idx] = sG[(size_t)i*4096+idx];
    for (int idx = t; idx < 2048; idx += 512) dB[(size_t)i*2048+idx] = sB[(size_t)i*2048+idx];
    return;
  }
  const float* Ge = sG + (size_t)(i-s)*4096;  // earlier
  const float* Gl = sG + (size_t)i*4096;      // later
  if (g == 0) mmNN<64>(tl, dG + (size_t)i*4096, 64, Ge, 64, Gl, 64);                             // G' = Ge @ Gl
  else        mm32NN<64>(tl, dB + (size_t)i*2048, 64, sB + (size_t)(i-s)*2048, 64, Gl, 64,
                         sB + (size_t)i*2048, 64);                                               // b' = be@Gl + bl
}

__global__ __launch_bounds__(256) void k_xb(const float* __restrict__ phiG, const float* __restrict__ phiB,
    const float* __restrict__ x0, float* __restrict__ ws)
{
  __shared__ float v[64];
  const int c = blockIdx.x, t = threadIdx.x;
  float* D = ws + OFF_XB + (size_t)c*2048;
  if (c == 0) {
    for (int idx = t; idx < 2048; idx += 256) D[idx] = x0[idx&63];
    return;
  }
  const float* G = phiG + (size_t)(c-1)*4096;
  const float* b = phiB + (size_t)(c-1)*2048;
  if (t < 64) {
    float acc = 0.f;
    for (int k = 0; k < 64; ++k) acc += x0[k]*G[k*64 + t];
    v[t] = acc;
  }
  __syncthreads();
  for (int idx = t; idx < 2048; idx += 256) D[idx] = v[idx&63] + b[idx];
}

__global__ __launch_bounds__(256) void k_xwalk(const float* __restrict__ ws_g, const float* __restrict__ ws_b,
    const float* __restrict__ ws_xb, float* __restrict__ outx)
{
  __shared__ float x[NB*LD], xn[NB*LD];
  const int c = blockIdx.x, t = threadIdx.x;
  const float* X0 = ws_xb + (size_t)c*2048;
  for (int idx = t; idx < 2048; idx += 256) x[(idx>>6)*LD+(idx&63)] = X0[idx];
  __syncthreads();
  for (int s = 0; s < CHUNK; ++s) {
    const size_t tt = (size_t)c*CHUNK + s;
    mm32NN<64>(t, xn, LD, x, LD, ws_g + tt*4096, 64, ws_b + tt*2048, 64);
    __syncthreads();
    for (int idx = t; idx < 2048; idx += 256) {
      const int i = idx>>6, d = idx&63;
      const float val = xn[i*LD+d];
      x[i*LD+d] = val;
      outx[(size_t)i*131072 + tt*64 + d] = val;
    }
    __syncthreads();
  }
}

__global__ __launch_bounds__(256) void k_final(const float* __restrict__ Cin, const float* __restrict__ x0,
    const float* __restrict__ outx, const float* __restrict__ outyn,
    float* __restrict__ outu, float* __restrict__ outyp, float* __restrict__ ws)
{
  __shared__ float xc[NB*LD], z[NB*LD], t1[NB*LD], t2[NB*LD];
  __shared__ float red4[4];
  const int tt = blockIdx.x, t = threadIdx.x;
  for (int idx = t; idx < 2048; idx += 256) {
    const int i = idx>>6, d = idx&63;
    xc[i*LD+d] = outx[(size_t)i*131072 + (size_t)tt*64 + d];
    z[i*LD+d]  = (tt == 0) ? x0[d] : outx[(size_t)i*131072 + (size_t)(tt-1)*64 + d];
  }
  __syncthreads();
  mm32TB<64>(t, t1, LD, xc, LD, ws + OFF_K + (size_t)tt*4096, 64, nullptr, 0, -1.0f);  // u
  mm32TB<64>(t, t2, LD, xc, LD, Cin, 64);                                              // y_pred
  __syncthreads();
  for (int idx = t; idx < 2048; idx += 256) {
    const int i = idx>>6, d = idx&63;
    outu[(size_t)i*131072 + (size_t)tt*64 + d]  = t1[i*LD+d];
    outyp[(size_t)i*131072 + (size_t)tt*64 + d] = t2[i*LD+d];
  }
  __syncthreads();
  mm32NN<64>(t, t2, LD, xc, LD, ws + OFF_Q, 64);     // x @ Q
  __syncthreads();
  const int i_ = t >> 3, lane8 = t & 7;
  float cpart = 0.f;
  for (int d = lane8; d < 64; d += 8) cpart += t2[i_*LD+d]*xc[i_*LD+d];
  __syncthreads();
  mm32NN<64>(t, t2, LD, t1, LD, ws + OFF_R, 64);     // u @ R
  __syncthreads();
  for (int d = lane8; d < 64; d += 8) cpart += t2[i_*LD+d]*t1[i_*LD+d];
  cpart += __shfl_down(cpart, 4, 8);
  cpart += __shfl_down(cpart, 2, 8);
  cpart += __shfl_down(cpart, 1, 8);
  if (lane8 == 0) ws[OFF_COST + (size_t)tt*32 + i_] = cpart;
  __syncthreads();
  mm32TB<64>(t, t2, LD, z, LD, ws + OFF_AEFF + (size_t)tt*4096, 64, z, LD, DT_C);      // x_pred
  __syncthreads();
  mm32TB<64>(t, t1, LD, t2, LD, Cin, 64, outyn + (size_t)tt*64, (size_t)131072, -1.0f);// resid = yn - x_pred C^T
  __syncthreads();
  mm32TB<64>(t, z, LD, t1, LD, ws + OFF_UV + (size_t)tt*8192 + 4096, 64);              // w = resid @ S_inv^T
  __syncthreads();
  float q = 0.f;
  for (int idx = t; idx < 2048; idx += 256) {
    const int p = (idx>>6)*LD + (idx&63);
    q += t1[p]*z[p];
  }
  q += __shfl_down(q, 32); q += __shfl_down(q, 16); q += __shfl_down(q, 8);
  q += __shfl_down(q, 4);  q += __shfl_down(q, 2);  q += __shfl_down(q, 1);
  if ((t & 63) == 0) red4[t>>6] = q;
  __syncthreads();
  if (t == 0) ws[OFF_QUAD + tt] = red4[0]+red4[1]+red4[2]+red4[3];
}

__global__ __launch_bounds__(256) void k_scalars(const float* __restrict__ ws, float* __restrict__ out)
{
  __shared__ float red[256];
  const int t = threadIdx.x;
  float q = 0.f;
  for (int i = t; i < 2048; i += 256) q += ws[OFF_QUAD + i];
  red[t] = q;
  __syncthreads();
  for (int s = 128; s > 0; s >>= 1) { if (t < s) red[t] += red[t+s]; __syncthreads(); }
  const float quadsum = red[0];
  __syncthreads();
  {
    const int b = t & 31, chunk = t >> 5;
    float a = 0.f;
    for (int j = 0; j < 256; ++j) a += ws[OFF_COST + (size_t)(chunk*256 + j)*32 + b];
    red[t] = a;
  }
  __syncthreads();
  if (t < 32) {
    float a = 0.f;
    for (int ch = 0; ch < 8; ++ch) a += red[ch*32 + t];
    red[t] = a;
  }
  __syncthreads();
  if (t == 0) {
    float cc = 0.f;
    for (int b = 0; b < 32; ++b) cc += red[b];
    out[1] = cc / 32.0f;
    const float ld = ws[OFF_LOGDET];
    out[0] = -0.5f*(quadsum + 2048.0f*(ld + 64.0f*LOG2PI)) / 2048.0f;
  }
}

// =====================================================================
extern "C" void kernel_launch(void* const* d_in, const int* in_sizes, int n_in,
                              void* d_out, int out_size, void* d_ws, size_t ws_size,
                              hipStream_t stream)
{
  (void)in_sizes; (void)n_in; (void)out_size; (void)ws_size;
  const float* y   = (const float*)d_in[0];
  const float* A   = (const float*)d_in[1];
  const float* Bi  = (const float*)d_in[2];
  const float* C   = (const float*)d_in[3];
  const float* LQ  = (const float*)d_in[4];
  const float* LR  = (const float*)d_in[5];
  const float* LV  = (const float*)d_in[6];
  const float* LQp = (const float*)d_in[7];
  const float* x0  = (const float*)d_in[8];
  const float* P0  = (const float*)d_in[9];
  float* out = (float*)d_out;
  float* ws  = (float*)d_ws;

  k_stats<<<256, 256, 0, stream>>>(y, ws);
  k_setup<<<1, 256, 0, stream>>>(A, Bi, LQ, LR, LV, LQp, ws);
  k_yn<<<4096, 256, 0, stream>>>(y, ws, out);

  // chain[j] = M^(2^j), j = 1..11 (16-block parallel squarings)
  for (int j = 1; j <= 11; ++j)
    k_sq<<<16, 256, 0, stream>>>(ws + OFF_CHAIN + (size_t)(j-1)*16384, ws + OFF_CHAIN + (size_t)j*16384);
  // fused power table (M^0..M^63) + boundary states SB_k = M^(64k) S0
  for (int j = 0; j <= 5; ++j)
    k_powbounds<<<6 << j, 256, 0, stream>>>(ws + OFF_CHAIN, ws, j);

  k_lqr<<<2048, 256, 0, stream>>>(A, Bi, ws);

  // KF covariance operator scan (OPS2 ping-pong aliased into the UV region,
  // which is dead until k_uvwalk writes it)
  k_ops2<<<NCH, 1024, 0, stream>>>(ws + OFF_AEFF, ws + OFF_QP, ws + OFF_OPS2);
  {
    float* pa = ws + OFF_OPS2;
    float* pb = pa + (size_t)NCH*12288;
    float* src = pa; float* dst = pb;
    for (int s = 1; s < NCH; s <<= 1) {
      k_scan2<<<NCH, 1024, 0, stream>>>(src, dst, s);
      float* tmp = src; src = dst; dst = tmp;
    }
    k_sb2<<<NCH, 256, 0, stream>>>(src, P0, ws);
  }
  k_uvwalk<<<NCH, 1024, 0, stream>>>(ws + OFF_AEFF, ws + OFF_QP, ws + OFF_SB2, ws + OFF_UV);
  k_kfper<<<2048, 256, 0, stream>>>(C, out + OOFF_YN, ws);

  // x-filter affine scan
  k_ops3<<<NCH, 1024, 0, stream>>>(ws + OFF_G, ws + OFF_B, ws + OFF_OPS3G, ws + OFF_OPS3B);
  {
    float* ga = ws + OFF_OPS3G; float* gb = ga + (size_t)NCH*4096;
    float* ba = ws + OFF_OPS3B; float* bb = ba + (size_t)NCH*2048;
    float *gs = ga, *gd = gb, *bs = ba, *bd = bb;
    for (int s = 1; s < NCH; s <<= 1) {
      k_scan3<<<NCH, 512, 0, stream>>>(gs, bs, gd, bd, s);
      float* t1p = gs; gs = gd; gd = t1p;
      float* t2p = bs; bs = bd; bd = t2p;
    }
    k_xb<<<NCH, 256, 0, stream>>>(gs, bs, x0, ws);
  }
  k_xwalk<<<NCH, 256, 0, stream>>>(ws + OFF_G, ws + OFF_B, ws + OFF_XB, out + OOFF_XF);

  // epilogue
  k_final<<<2048, 256, 0, stream>>>(C, x0, out + OOFF_XF, out + OOFF_YN, out + OOFF_U, out + OOFF_YP, ws);
  k_scalars<<<1, 256, 0, stream>>>(ws, out);
}

// Round 16
// 2276.244 us; speedup vs baseline: 1.0804x; 1.0136x over previous
//
#include <hip/hip_runtime.h>
#include <math.h>

#define XD 64
#define SEQL 2048
#define NB 32
#define DT_C  (1.0f/1024.0f)
#define EPS_C 1e-4f
#define LD 68
#define LOG2PI 1.8378770664093453f
#define CHUNK 8
#define NCH 256

// ---------------- workspace offsets (floats) ----------------
#define OFF_PARTIAL 0u
#define OFF_MEAN    32768u
#define OFF_STD     32832u
#define OFF_Q       32896u
#define OFF_R       36992u
#define OFF_VM      41088u
#define OFF_QP      45184u
#define OFF_RIREG   49280u
#define OFF_LOGDET  53376u
#define OFF_CHAIN   53440u                      /* 12*16384 */
#define OFF_POW     250048u                     /* 64*16384 */
#define OFF_BOUNDS  1298624u                    /* 33*8192 */
#define OFF_K       1568960u                    /* 2048*4096 */
#define OFF_AEFF    9957568u                    /* 2048*4096 */
#define OFF_UV      18346176u                   /* 2048*8192 ; Kg/Sinv overlay; OPS2 aliases here pre-uvwalk */
#define OFF_G       35123392u                   /* 2048*4096 */
#define OFF_B       43512000u                   /* 2048*2048 */
#define OFF_OPS2    OFF_UV                      /* 2*256*12288 aliased into UV (dead until uvwalk) */
#define OFF_OPS3G   47706304u                   /* 2*256*4096 */
#define OFF_OPS3B   49803456u                   /* 2*256*2048 */
#define OFF_SB2     50852032u                   /* 256*8192 */
#define OFF_XB      52949184u                   /* 256*2048 */
#define OFF_QUAD    53473472u                   /* 2048 */
#define OFF_COST    53475520u                   /* 2048*32 */
#define OFF_BRI     53541056u                   /* 4096 : B @ inv(R+eps I) */

// ---------------- output offsets (floats) ----------------
#define OOFF_XF 2
#define OOFF_U  4194306
#define OOFF_YP 8388610
#define OOFF_YN 12582914

// =====================================================================
// 64x64 matmul helpers: 256 threads, 16 outputs/thread (4x4 tile).
// out = alpha*(op(A)@op(B)) [+ addC]
// =====================================================================
template<int KD>
__device__ __forceinline__ void mmNN(int t, float* __restrict__ out, int ldo,
    const float* __restrict__ A, int lda, const float* __restrict__ B, int ldb,
    const float* __restrict__ addC = nullptr, int ldc = 0, float alpha = 1.0f)
{
  const int r0 = (t >> 4) << 2, c0 = (t & 15) << 2;
  float acc[4][4] = {};
  for (int k = 0; k < KD; k += 4) {
    float a_[4][4];
    #pragma unroll
    for (int i = 0; i < 4; ++i) {
      const float4 x = *(const float4*)&A[(r0+i)*lda + k];
      a_[i][0]=x.x; a_[i][1]=x.y; a_[i][2]=x.z; a_[i][3]=x.w;
    }
    #pragma unroll
    for (int kk = 0; kk < 4; ++kk) {
      const float4 bv = *(const float4*)&B[(k+kk)*ldb + c0];
      #pragma unroll
      for (int i = 0; i < 4; ++i) {
        const float a = a_[i][kk];
        acc[i][0] += a*bv.x; acc[i][1] += a*bv.y; acc[i][2] += a*bv.z; acc[i][3] += a*bv.w;
      }
    }
  }
  #pragma unroll
  for (int i = 0; i < 4; ++i)
    #pragma unroll
    for (int j = 0; j < 4; ++j) {
      float v = alpha*acc[i][j];
      if (addC) v += addC[(r0+i)*ldc + (c0+j)];
      out[(r0+i)*ldo + (c0+j)] = v;
    }
}

template<int KD>
__device__ __forceinline__ void mmTA(int t, float* __restrict__ out, int ldo,
    const float* __restrict__ A, int lda, const float* __restrict__ B, int ldb,
    const float* __restrict__ addC = nullptr, int ldc = 0, float alpha = 1.0f)
{ // out = A^T @ B  (A is KD x 64)
  const int r0 = (t >> 4) << 2, c0 = (t & 15) << 2;
  float acc[4][4] = {};
  for (int k = 0; k < KD; k += 4) {
    #pragma unroll
    for (int kk = 0; kk < 4; ++kk) {
      const float4 av4 = *(const float4*)&A[(k+kk)*lda + r0];
      const float4 bv4 = *(const float4*)&B[(k+kk)*ldb + c0];
      const float av[4] = {av4.x, av4.y, av4.z, av4.w};
      const float bv[4] = {bv4.x, bv4.y, bv4.z, bv4.w};
      #pragma unroll
      for (int i = 0; i < 4; ++i)
        #pragma unroll
        for (int j = 0; j < 4; ++j)
          acc[i][j] += av[i]*bv[j];
    }
  }
  #pragma unroll
  for (int i = 0; i < 4; ++i)
    #pragma unroll
    for (int j = 0; j < 4; ++j) {
      float v = alpha*acc[i][j];
      if (addC) v += addC[(r0+i)*ldc + (c0+j)];
      out[(r0+i)*ldo + (c0+j)] = v;
    }
}

template<int KD>
__device__ __forceinline__ void mmTB(int t, float* __restrict__ out, int ldo,
    const float* __restrict__ A, int lda, const float* __restrict__ B, int ldb,
    const float* __restrict__ addC = nullptr, int ldc = 0, float alpha = 1.0f)
{ // out = A @ B^T  (B is 64 x KD)
  const int r0 = (t >> 4) << 2, c0 = (t & 15) << 2;
  float acc[4][4] = {};
  for (int k = 0; k < KD; k += 4) {
    float a_[4][4], b_[4][4];
    #pragma unroll
    for (int i = 0; i < 4; ++i) {
      const float4 x = *(const float4*)&A[(r0+i)*lda + k];
      a_[i][0]=x.x; a_[i][1]=x.y; a_[i][2]=x.z; a_[i][3]=x.w;
    }
    #pragma unroll
    for (int j = 0; j < 4; ++j) {
      const float4 x = *(const float4*)&B[(c0+j)*ldb + k];
      b_[j][0]=x.x; b_[j][1]=x.y; b_[j][2]=x.z; b_[j][3]=x.w;
    }
    #pragma unroll
    for (int i = 0; i < 4; ++i)
      #pragma unroll
      for (int j = 0; j < 4; ++j)
        acc[i][j] += a_[i][0]*b_[j][0] + a_[i][1]*b_[j][1] + a_[i][2]*b_[j][2] + a_[i][3]*b_[j][3];
  }
  #pragma unroll
  for (int i = 0; i < 4; ++i)
    #pragma unroll
    for (int j = 0; j < 4; ++j) {
      float v = alpha*acc[i][j];
      if (addC) v += addC[(r0+i)*ldc + (c0+j)];
      out[(r0+i)*ldo + (c0+j)] = v;
    }
}

// b_out = 0.5*(X + X^T) tile-based (4x4 tiles, float4 row-major accesses).
__device__ __forceinline__ void symTile(int t, float* __restrict__ outb, const float* __restrict__ X)
{
  const int r0 = (t >> 4) << 2, c0 = (t & 15) << 2;
  float xa[4][4], xb[4][4];
  #pragma unroll
  for (int i = 0; i < 4; ++i) {
    const float4 u = *(const float4*)&X[(r0+i)*LD + c0];
    xa[i][0]=u.x; xa[i][1]=u.y; xa[i][2]=u.z; xa[i][3]=u.w;
    const float4 v = *(const float4*)&X[(c0+i)*LD + r0];
    xb[i][0]=v.x; xb[i][1]=v.y; xb[i][2]=v.z; xb[i][3]=v.w;
  }
  #pragma unroll
  for (int i = 0; i < 4; ++i) {
    float4 o;
    o.x = 0.5f*(xa[i][0] + xb[0][i]);
    o.y = 0.5f*(xa[i][1] + xb[1][i]);
    o.z = 0.5f*(xa[i][2] + xb[2][i]);
    o.w = 0.5f*(xa[i][3] + xb[3][i]);
    *(float4*)&outb[(r0+i)*LD + c0] = o;
  }
}

// 32x64 = (32xKD)@(KDx64) variants: 256 threads, 8 outputs (2x4 tile)
template<int KD>
__device__ __forceinline__ void mm32NN(int t, float* __restrict__ out, int ldo,
    const float* __restrict__ A, int lda, const float* __restrict__ B, int ldb,
    const float* __restrict__ addC = nullptr, int ldc = 0, float alpha = 1.0f)
{
  const int r0 = (t >> 4) << 1, c0 = (t & 15) << 2;
  float acc[2][4] = {};
  for (int k = 0; k < KD; k += 4) {
    float a_[2][4];
    #pragma unroll
    for (int i = 0; i < 2; ++i) {
      const float4 x = *(const float4*)&A[(r0+i)*lda + k];
      a_[i][0]=x.x; a_[i][1]=x.y; a_[i][2]=x.z; a_[i][3]=x.w;
    }
    #pragma unroll
    for (int kk = 0; kk < 4; ++kk) {
      const float4 bv = *(const float4*)&B[(k+kk)*ldb + c0];
      #pragma unroll
      for (int i = 0; i < 2; ++i) {
        const float a = a_[i][kk];
        acc[i][0] += a*bv.x; acc[i][1] += a*bv.y; acc[i][2] += a*bv.z; acc[i][3] += a*bv.w;
      }
    }
  }
  #pragma unroll
  for (int i = 0; i < 2; ++i)
    #pragma unroll
    for (int j = 0; j < 4; ++j) {
      float v = alpha*acc[i][j];
      if (addC) v += addC[(r0+i)*ldc + (c0+j)];
      out[(r0+i)*ldo + (c0+j)] = v;
    }
}

template<int KD>
__device__ __forceinline__ void mm32TB(int t, float* __restrict__ out, int ldo,
    const float* __restrict__ A, size_t lda, const float* __restrict__ B, int ldb,
    const float* __restrict__ addC = nullptr, size_t ldc = 0, float alpha = 1.0f)
{ // out = A @ B^T
  const int r0 = (t >> 4) << 1, c0 = (t & 15) << 2;
  float acc[2][4] = {};
  for (int k = 0; k < KD; k += 4) {
    float a_[2][4], b_[4][4];
    #pragma unroll
    for (int i = 0; i < 2; ++i) {
      const float4 x = *(const float4*)&A[(size_t)(r0+i)*lda + k];
      a_[i][0]=x.x; a_[i][1]=x.y; a_[i][2]=x.z; a_[i][3]=x.w;
    }
    #pragma unroll
    for (int j = 0; j < 4; ++j) {
      const float4 x = *(const float4*)&B[(c0+j)*ldb + k];
      b_[j][0]=x.x; b_[j][1]=x.y; b_[j][2]=x.z; b_[j][3]=x.w;
    }
    #pragma unroll
    for (int i = 0; i < 2; ++i)
      #pragma unroll
      for (int j = 0; j < 4; ++j)
        acc[i][j] += a_[i][0]*b_[j][0] + a_[i][1]*b_[j][1] + a_[i][2]*b_[j][2] + a_[i][3]*b_[j][3];
  }
  #pragma unroll
  for (int i = 0; i < 2; ++i)
    #pragma unroll
    for (int j = 0; j < 4; ++j) {
      float v = alpha*acc[i][j];
      if (addC) v += addC[(size_t)(r0+i)*ldc + (c0+j)];
      out[(r0+i)*ldo + (c0+j)] = v;
    }
}

// Gauss-Jordan (no pivoting): RHS <- Am^{-1} RHS ; destroys Am. 256 threads.
// Used only in the single-block k_setup (cost negligible).
__device__ __forceinline__ void gj64(int t, float* __restrict__ Am, float* __restrict__ R)
{
  const int r = t >> 2;
  const int c0 = (t & 3) << 4;
  for (int k = 0; k < 64; ++k) {
    __syncthreads();
    const float pv = Am[k*LD + k];
    const float f = Am[r*LD + k] / pv;
    if (r != k) {
      #pragma unroll
      for (int c = 0; c < 16; c += 4) {
        float4 ak = *(const float4*)&Am[k*LD + c0 + c];
        float4 ar = *(float4*)&Am[r*LD + c0 + c];
        ar.x -= f*ak.x; ar.y -= f*ak.y; ar.z -= f*ak.z; ar.w -= f*ak.w;
        *(float4*)&Am[r*LD + c0 + c] = ar;
        float4 rk = *(const float4*)&R[k*LD + c0 + c];
        float4 rr = *(float4*)&R[r*LD + c0 + c];
        rr.x -= f*rk.x; rr.y -= f*rk.y; rr.z -= f*rk.z; rr.w -= f*rk.w;
        *(float4*)&R[r*LD + c0 + c] = rr;
      }
    }
  }
  __syncthreads();
  const float dinv = 1.0f / Am[r*LD + r];
  #pragma unroll
  for (int c = 0; c < 16; c += 4) {
    float4 rr = *(float4*)&R[r*LD + c0 + c];
    rr.x *= dinv; rr.y *= dinv; rr.z *= dinv; rr.w *= dinv;
    *(float4*)&R[r*LD + c0 + c] = rr;
  }
  __syncthreads();
}

// =====================================================================
// IN-PLACE blocked Gauss-Jordan INVERSION (sweep), 8x8 pivot blocks:
// Am <- Am^{-1}. 256 threads, 3 barriers per block-step. No RHS array.
// Per block-step with W = inv(pivot block B):
//   pivot rows:      non-pivot cols -> W @ oldRows ; pivot cols -> W
//   non-pivot row i: C_i = old A[i][K..K+7];
//                    non-pivot cols -> row - C_i @ newPivotRows
//                    pivot cols     -> -C_i @ W
// Verified against scalar in-place GJ (2x2 analytic check).
// =====================================================================
__device__ __forceinline__ void gji8(int t, float* __restrict__ Am)
{
  const int r  = t >> 2;           // trailing row 0..63
  const int c0 = (t & 3) << 4;     // trailing 16-col quadrant
  const int pj = (t >> 4) & 7;     // panel pivot row (threads 0..127 active)
  const int c4 = (t & 15) << 2;    // panel float4 col
  const int lane = t & 63;
  const int li = lane >> 3, lj = lane & 7;
  for (int kb = 0; kb < 8; ++kb) {
    const int K = kb << 3;
    __syncthreads();               // prev trailing update complete
    const bool inK = ((unsigned)(r - K)) < 8u;
    // hoisted multipliers C_i (old pivot-col block of own non-pivot row)
    float4 f0 = make_float4(0.f,0.f,0.f,0.f), f1 = f0;
    if (!inK) {
      f0 = *(const float4*)&Am[r*LD + K];
      f1 = *(const float4*)&Am[r*LD + K + 4];
    }
    // ---- every wave: W = inv(Am[K..K+7][K..K+7]) in registers ----
    float a = Am[(K+li)*LD + K + lj];
    float w = (li == lj) ? 1.0f : 0.0f;
    #pragma unroll
    for (int p = 0; p < 8; ++p) {
      const float pv  = __shfl(a, p*8 + p, 64);
      const float pvr = __builtin_amdgcn_rcpf(pv);
      const float aip = __shfl(a, li*8 + p, 64);
      const float apj = __shfl(a, p*8 + lj, 64);
      const float wpj = __shfl(w, p*8 + lj, 64);
      const float fi  = aip * pvr;
      if (li == p) { a *= pvr; w *= pvr; }
      else         { a -= fi * apj; w -= fi * wpj; }
    }
    float wrow[8];
    #pragma unroll
    for (int m = 0; m < 8; ++m) wrow[m] = __shfl(w, pj*8 + m, 64);
    // ---- panel into regs (threads 0..127): newPivotRow[K+pj][c4..c4+3] ----
    float4 acc = make_float4(0.f,0.f,0.f,0.f);
    if (t < 128) {
      #pragma unroll
      for (int m = 0; m < 8; ++m) {
        const float4 rv = *(const float4*)&Am[(K+m)*LD + c4];
        acc.x += wrow[m]*rv.x; acc.y += wrow[m]*rv.y; acc.z += wrow[m]*rv.z; acc.w += wrow[m]*rv.w;
      }
      const unsigned dp = (unsigned)(c4 - K);
      if (dp < 8u) acc = make_float4(wrow[dp], wrow[dp+1], wrow[dp+2], wrow[dp+3]);
    }
    __syncthreads();               // all readers done with old pivot rows
    if (t < 128) *(float4*)&Am[(K+pj)*LD + c4] = acc;
    __syncthreads();               // new pivot rows visible
    // ---- trailing: non-pivot rows, ALL 64 cols ----
    if (!inK) {
      const float fj[8] = {f0.x, f0.y, f0.z, f0.w, f1.x, f1.y, f1.z, f1.w};
      #pragma unroll
      for (int c = 0; c < 16; c += 4) {
        const int cab = c0 + c;
        const bool isPiv = ((unsigned)(cab - K)) < 8u;
        float4 v = isPiv ? make_float4(0.f,0.f,0.f,0.f) : *(float4*)&Am[r*LD + cab];
        #pragma unroll
        for (int j = 0; j < 8; ++j) {
          const float4 p4 = *(const float4*)&Am[(K+j)*LD + cab];
          v.x -= fj[j]*p4.x; v.y -= fj[j]*p4.y; v.z -= fj[j]*p4.z; v.w -= fj[j]*p4.w;
        }
        *(float4*)&Am[r*LD + cab] = v;
      }
    }
  }
  __syncthreads();
}

// =====================================================================
// Kernels
// =====================================================================

__global__ __launch_bounds__(256) void k_stats(const float* __restrict__ y, float* __restrict__ ws)
{
  __shared__ float sbuf[4][128];
  const int t = threadIdx.x, blk = blockIdx.x;
  const int d = t & 63, g = t >> 6;
  float s = 0.f, s2 = 0.f;
  for (int r = g; r < 256; r += 4) {
    const float v = y[(size_t)(blk*256 + r)*64 + d];
    s += v; s2 += v*v;
  }
  sbuf[g][d] = s; sbuf[g][64+d] = s2;
  __syncthreads();
  if (t < 128) ws[OFF_PARTIAL + (size_t)blk*128 + t] = sbuf[0][t]+sbuf[1][t]+sbuf[2][t]+sbuf[3][t];
}

__global__ __launch_bounds__(256) void k_setup(
    const float* __restrict__ A, const float* __restrict__ Bi,
    const float* __restrict__ LQ, const float* __restrict__ LR,
    const float* __restrict__ LV, const float* __restrict__ LQp,
    float* __restrict__ ws)
{
  __shared__ float b1[64*LD], b2[64*LD], b3[64*LD], b4[64*LD], bQ[64*LD];
  __shared__ float sred[128];
  const int t = threadIdx.x;

  if (t < 128) {
    float acc = 0.f;
    for (int p = 0; p < 256; ++p) acc += ws[OFF_PARTIAL + (size_t)p*128 + t];
    sred[t] = acc;
  }
  __syncthreads();
  if (t < 64) {
    const float mean = sred[t] * (1.0f/65536.0f);
    const float var = (sred[64+t] - 65536.0f*mean*mean) * (1.0f/65535.0f);
    ws[OFF_MEAN + t] = mean;
    ws[OFF_STD + t] = sqrtf(var);
  }

  mmTB<64>(t, bQ, LD, LQ, 64, LQ, 64);              // Q
  mmTB<64>(t, b3, LD, LR, 64, LR, 64);              // R
  mmTB<64>(t, ws+OFF_VM, 64, LV, 64, LV, 64);       // V
  mmTB<64>(t, ws+OFF_QP, 64, LQp, 64, LQp, 64);     // Q_proc
  __syncthreads();
  for (int idx = t; idx < 4096; idx += 256) {
    const int r = idx>>6, c = idx&63;
    ws[OFF_Q + idx] = bQ[r*LD+c];
    ws[OFF_R + idx] = b3[r*LD+c];
    b1[r*LD+c] = b3[r*LD+c] + ((r==c)?EPS_C:0.f);
    b2[r*LD+c] = (r==c)?1.f:0.f;
  }
  gj64(t, b1, b2);                                   // b2 = inv(R + eps I)
  mmNN<64>(t, b4, LD, Bi, 64, b2, LD);               // b4 = BRI = B @ inv(R+eps)
  __syncthreads();
  for (int idx = t; idx < 4096; idx += 256) {
    ws[OFF_RIREG + idx] = b2[(idx>>6)*LD+(idx&63)];
    ws[OFF_BRI + idx]   = b4[(idx>>6)*LD+(idx&63)];
  }
  __syncthreads();
  for (int idx = t; idx < 4096; idx += 256) {
    const int r = idx>>6, c = idx&63;
    b1[r*LD+c] = b3[r*LD+c];
    b2[r*LD+c] = (r==c)?1.f:0.f;
  }
  gj64(t, b1, b2);                                   // b2 = inv(R)
  mmTB<64>(t, b3, LD, b2, LD, Bi, 64);               // b3 = Rinv @ B^T
  __syncthreads();
  mmNN<64>(t, b4, LD, Bi, 64, b3, LD);               // b4 = B Rinv B^T
  mmTB<64>(t, b1, LD, LV, 64, LV, 64);               // b1 = V (for logdet)
  __syncthreads();
  if (t < 64) b1[t*LD+t] += EPS_C;
  {
    const int r = t >> 2, c0 = (t & 3) << 4;
    float lsum = 0.f;
    for (int k = 0; k < 64; ++k) {
      __syncthreads();
      const float pv = b1[k*LD+k];
      lsum += logf(pv);
      const float f = b1[r*LD+k] / pv;
      if (r != k) {
        #pragma unroll
        for (int c = 0; c < 16; c += 4) {
          float4 ak = *(const float4*)&b1[k*LD+c0+c];
          float4 ar = *(float4*)&b1[r*LD+c0+c];
          ar.x -= f*ak.x; ar.y -= f*ak.y; ar.z -= f*ak.z; ar.w -= f*ak.w;
          *(float4*)&b1[r*LD+c0+c] = ar;
        }
      }
    }
    if (t == 0) ws[OFF_LOGDET] = lsum;
  }
  __syncthreads();
  // M = I + DT*[[A, -BRB],[-Q, -A^T]]  -> chain[0]
  float* M0 = ws + OFF_CHAIN;
  for (int idx = t; idx < 16384; idx += 256) {
    const int i = idx >> 7, j = idx & 127;
    float v;
    if (i < 64) v = (j < 64) ? (((i==j)?1.f:0.f) + DT_C*A[i*64+j]) : (-DT_C*b4[i*LD + (j-64)]);
    else        v = (j < 64) ? (-DT_C*bQ[(i-64)*LD + j]) : (((i==j)?1.f:0.f) - DT_C*A[(j-64)*64 + (i-64)]);
    M0[idx] = v;
  }
  for (int idx = t; idx < 16384; idx += 256) {
    const int i = idx >> 7, j = idx & 127;
    ws[OFF_POW + idx] = (i==j)?1.f:0.f;              // M^0 = I
  }
  for (int idx = t; idx < 8192; idx += 256) {
    const int i = idx >> 6, j = idx & 63;
    ws[OFF_BOUNDS + idx] = (i < 64) ? ((i==j)?1.f:0.f) : bQ[(i-64)*LD + j];   // S0 = [I; Q]
  }
}

__global__ __launch_bounds__(256) void k_yn(const float* __restrict__ y, const float* __restrict__ ws, float* __restrict__ out)
{
  const size_t i0 = ((size_t)blockIdx.x*256 + threadIdx.x)*4;
  const int d = (int)(i0 & 63);
  const float4 v = *(const float4*)&y[i0];
  const float4 m = *(const float4*)&ws[OFF_MEAN + d];
  const float4 s = *(const float4*)&ws[OFF_STD + d];
  float* o = out + OOFF_YN + i0;
  o[0] = (v.x - m.x)/(s.x + EPS_C);
  o[1] = (v.y - m.y)/(s.y + EPS_C);
  o[2] = (v.z - m.z)/(s.z + EPS_C);
  o[3] = (v.w - m.w)/(s.w + EPS_C);
}

__global__ __launch_bounds__(256) void k_sq(const float* __restrict__ src, float* __restrict__ dst)
{ // dst = src @ src (128x128); grid 16, 8 rows/block
  const int t = threadIdx.x;
  const int r = blockIdx.x*8 + (t >> 5);
  const int c0 = (t & 31) << 2;
  float acc[4] = {0.f,0.f,0.f,0.f};
  for (int k = 0; k < 128; k += 4) {
    const float4 a4 = *(const float4*)&src[r*128 + k];
    const float av[4] = {a4.x, a4.y, a4.z, a4.w};
    #pragma unroll
    for (int kk = 0; kk < 4; ++kk) {
      const float4 bv = *(const float4*)&src[(k+kk)*128 + c0];
      acc[0] += av[kk]*bv.x; acc[1] += av[kk]*bv.y; acc[2] += av[kk]*bv.z; acc[3] += av[kk]*bv.w;
    }
  }
  float4 o; o.x=acc[0]; o.y=acc[1]; o.z=acc[2]; o.w=acc[3];
  *(float4*)&dst[r*128 + c0] = o;
}

__global__ __launch_bounds__(256) void k_powbounds(const float* __restrict__ chain, float* __restrict__ ws, int level)
{ // fused: blocks [0, 4<<level) = pow level; blocks [4<<level, 6<<level) = bounds level
  const int nbp = 4 << level;
  const int t = threadIdx.x;
  if ((int)blockIdx.x < nbp) {
    // ---- pow: powt[i + 2^level] = chain[level] @ powt[i] ----
    const float* chainj = chain + (size_t)level*16384;
    float* powt = ws + OFF_POW;
    const int i = blockIdx.x >> 2, sub = blockIdx.x & 3;
    const float* Bm = powt + (size_t)i*16384;
    float* D = powt + (size_t)(i + (1<<level))*16384;
    const int r0 = sub*32 + ((t >> 4) << 1);
    const int c0 = (t & 15) << 3;
    float acc[2][8] = {};
    for (int k = 0; k < 128; k += 4) {
      float a_[2][4];
      {
        const float4 x = *(const float4*)&chainj[r0*128 + k];
        a_[0][0]=x.x; a_[0][1]=x.y; a_[0][2]=x.z; a_[0][3]=x.w;
        const float4 y2 = *(const float4*)&chainj[(r0+1)*128 + k];
        a_[1][0]=y2.x; a_[1][1]=y2.y; a_[1][2]=y2.z; a_[1][3]=y2.w;
      }
      #pragma unroll
      for (int kk = 0; kk < 4; ++kk) {
        const float4 b0 = *(const float4*)&Bm[(k+kk)*128 + c0];
        const float4 b1v = *(const float4*)&Bm[(k+kk)*128 + c0 + 4];
        #pragma unroll
        for (int i2 = 0; i2 < 2; ++i2) {
          const float a = a_[i2][kk];
          acc[i2][0] += a*b0.x; acc[i2][1] += a*b0.y; acc[i2][2] += a*b0.z; acc[i2][3] += a*b0.w;
          acc[i2][4] += a*b1v.x; acc[i2][5] += a*b1v.y; acc[i2][6] += a*b1v.z; acc[i2][7] += a*b1v.w;
        }
      }
    }
    #pragma unroll
    for (int i2 = 0; i2 < 2; ++i2)
      #pragma unroll
      for (int j = 0; j < 8; ++j)
        D[(r0+i2)*128 + c0 + j] = acc[i2][j];
  } else {
    // ---- bounds: bounds[k + 2^level] = chain[6+level] @ bounds[k] ----
    const int bb = blockIdx.x - nbp;
    const int kb = bb >> 1, sub = bb & 1;
    const int dsti = kb + (1 << level);
    if (dsti > 32) return;
    const float* chainp = chain + (size_t)(6+level)*16384;
    const float* S = ws + OFF_BOUNDS + (size_t)kb*8192;
    float* D = ws + OFF_BOUNDS + (size_t)dsti*8192;
    const int r0 = sub*64 + ((t >> 4) << 2);
    const int c0 = (t & 15) << 2;
    float acc[4][4] = {};
    for (int k = 0; k < 128; k += 4) {
      float a_[4][4];
      #pragma unroll
      for (int i = 0; i < 4; ++i) {
        const float4 x = *(const float4*)&chainp[(r0+i)*128 + k];
        a_[i][0]=x.x; a_[i][1]=x.y; a_[i][2]=x.z; a_[i][3]=x.w;
      }
      #pragma unroll
      for (int kk = 0; kk < 4; ++kk) {
        const float4 bv = *(const float4*)&S[(k+kk)*64 + c0];
        #pragma unroll
        for (int i = 0; i < 4; ++i) {
          const float a = a_[i][kk];
          acc[i][0] += a*bv.x; acc[i][1] += a*bv.y; acc[i][2] += a*bv.z; acc[i][3] += a*bv.w;
        }
      }
    }
    #pragma unroll
    for (int i = 0; i < 4; ++i)
      #pragma unroll
      for (int j = 0; j < 4; ++j)
        D[(r0+i)*64 + c0 + j] = acc[i][j];
  }
}

__global__ __launch_bounds__(256) void k_lqr(const float* __restrict__ Ain, const float* __restrict__ Bin, float* __restrict__ ws)
{ // per-t: S = M^r @ SB_k ; Uinv (in-place) ; X = V Uinv ; P ; bp ; {K, BRIbp}
  __shared__ float b1[64*LD], b2[64*LD], b3[64*LD];
  const int t = threadIdx.x, tt = blockIdx.x;
  const int tp1 = tt + 1, kc = tp1 >> 6, rr = tp1 & 63;
  const float* Mr = ws + OFF_POW + (size_t)rr*16384;
  const float* SB = ws + OFF_BOUNDS + (size_t)kc*8192;
  mmNN<128>(t, b1, LD, Mr, 128, SB, 64);            // b1 = U = (Mr@SB)[0:64]
  mmNN<128>(t, b3, LD, Mr + 8192, 128, SB, 64);     // b3 = V = (Mr@SB)[64:128]
  gji8(t, b1);                                      // b1 = U^{-1} (leading sync inside)
  mmNN<64>(t, b2, LD, b3, LD, b1, LD);              // b2 = X = V @ Uinv
  __syncthreads();
  symTile(t, b3, b2);                               // b3 = P = sym(X)  (V dead)
  __syncthreads();
  mmTA<64>(t, b1, LD, Bin, 64, b3, LD);             // b1 = bp = B^T P  (Uinv dead)
  __syncthreads();
  mmNN<64>(t, b2, LD, ws+OFF_RIREG, 64, b1, LD);    // b2 = K = RIREG @ bp
  mmNN<64>(t, b3, LD, ws+OFF_BRI, 64, b1, LD);      // b3 = BRI @ bp
  __syncthreads();
  float* Kout = ws + OFF_K + (size_t)tt*4096;
  float* Ae   = ws + OFF_AEFF + (size_t)tt*4096;
  for (int idx = t; idx < 4096; idx += 256) {
    const int p = (idx>>6)*LD + (idx&63);
    Kout[idx] = b2[p];
    Ae[idx]   = Ain[idx] - b3[p];
  }
}

__global__ __launch_bounds__(1024) void k_ops2(const float* __restrict__ ws_aeff, const float* __restrict__ ws_qp, float* __restrict__ dstE)
{ // per-chunk KF transfer-operator product (E,W,F)
  __shared__ float E[64*LD], W[64*LD], F[64*LD], T1[64*LD], T2[64*LD], T3[64*LD], T4[64*LD];
  const int t = threadIdx.x, c = blockIdx.x, g = t >> 8, tl = t & 255;
  for (int idx = t; idx < 4096; idx += 1024) {
    const int r = idx>>6, cc = idx&63; const float id = (r==cc)?1.f:0.f;
    E[r*LD+cc] = id; W[r*LD+cc] = 0.f; F[r*LD+cc] = id;
  }
  __syncthreads();
  for (int s = 0; s < CHUNK; ++s) {
    const float* Ae = ws_aeff + ((size_t)c*CHUNK + s)*4096;
    if (g == 0)      mmNN<64>(tl, T1, LD, Ae, 64, E, LD);
    else if (g == 1) mmNN<64>(tl, T2, LD, Ae, 64, W, LD);
    else if (g == 2) mmNN<64>(tl, T3, LD, ws_qp, 64, F, LD);
    else             mmTA<64>(tl, T4, LD, Ae, 64, F, LD);
    __syncthreads();
    for (int idx = t; idx < 4096; idx += 1024) {
      const int p = (idx>>6)*LD + (idx&63);
      E[p] += DT_C*T1[p];
      W[p] += DT_C*(T2[p] + T3[p]);
      F[p] -= DT_C*T4[p];
    }
    __syncthreads();
  }
  float* dst = dstE + (size_t)c*12288;
  for (int idx = t; idx < 4096; idx += 1024) {
    const int p = (idx>>6)*LD + (idx&63);
    dst[idx] = E[p]; dst[4096+idx] = W[p]; dst[8192+idx] = F[p];
  }
}

__global__ __launch_bounds__(1024) void k_scan2(const float* __restrict__ src, float* __restrict__ dst, int s)
{ // Hillis-Steele compose of (E,W,F) ops; op[i] (later) after op[i-s] (earlier)
  __shared__ float t1[64*LD], t2[64*LD];
  const int i = blockIdx.x, t = threadIdx.x, g = t>>8, tl = t&255;
  const float* si = src + (size_t)i*12288;
  float* di = dst + (size_t)i*12288;
  if (i < s) {
    for (int idx = t; idx < 12288; idx += 1024) di[idx] = si[idx];
    return;
  }
  const float* sj = src + (size_t)(i-s)*12288;
  if (g == 0)      mmNN<64>(tl, di, 64, si, 64, sj, 64);                   // E' = E2 E1
  else if (g == 1) mmNN<64>(tl, t1, LD, si, 64, sj+4096, 64);              // E2 W1
  else if (g == 2) mmNN<64>(tl, t2, LD, si+4096, 64, sj+8192, 64);         // W2 F1
  else             mmNN<64>(tl, di+8192, 64, si+8192, 64, sj+8192, 64);    // F' = F2 F1
  __syncthreads();
  for (int idx = t; idx < 4096; idx += 1024) {
    const int p = (idx>>6)*LD + (idx&63);
    di[4096+idx] = t1[p] + t2[p];
  }
}

__global__ __launch_bounds__(256) void k_sb2(const float* __restrict__ phi, const float* __restrict__ P0, float* __restrict__ ws)
{ // KF boundary states: SB[c] = Phi_{c-1} @ [I; P0]
  const int c = blockIdx.x, t = threadIdx.x;
  float* D = ws + OFF_SB2 + (size_t)c*8192;
  if (c == 0) {
    for (int idx = t; idx < 4096; idx += 256) {
      const int r = idx>>6, cc = idx&63;
      D[idx] = (r==cc)?1.f:0.f;
      D[4096+idx] = P0[idx];
    }
    return;
  }
  const float* ph = phi + (size_t)(c-1)*12288;
  mmNN<64>(t, D, 64, ph+4096, 64, P0, 64, ph, 64);    // U = W@P0 + E
  mmNN<64>(t, D+4096, 64, ph+8192, 64, P0, 64);       // V = F@P0
}

__global__ __launch_bounds__(1024) void k_uvwalk(const float* __restrict__ ws_aeff, const float* __restrict__ ws_qp,
    const float* __restrict__ ws_sb2, float* __restrict__ ws_uv)
{
  __shared__ float U[64*LD], V[64*LD], T1[64*LD], T2[64*LD], T3[64*LD];
  const int c = blockIdx.x, t = threadIdx.x, g = t>>8, tl = t&255;
  const float* S = ws_sb2 + (size_t)c*8192;
  for (int idx = t; idx < 4096; idx += 1024) {
    const int p = (idx>>6)*LD + (idx&63);
    U[p] = S[idx]; V[p] = S[4096+idx];
  }
  __syncthreads();
  for (int s = 0; s < CHUNK; ++s) {
    const size_t tt = (size_t)c*CHUNK + s;
    const float* Ae = ws_aeff + tt*4096;
    if (g == 0)      mmNN<64>(tl, T1, LD, Ae, 64, U, LD);
    else if (g == 1) mmNN<64>(tl, T2, LD, ws_qp, 64, V, LD);
    else if (g == 2) mmTA<64>(tl, T3, LD, Ae, 64, V, LD);
    __syncthreads();
    float* O = ws_uv + tt*8192;
    for (int idx = t; idx < 4096; idx += 1024) {
      const int p = (idx>>6)*LD + (idx&63);
      const float un = U[p] + DT_C*(T1[p] + T2[p]);
      const float vn = V[p] - DT_C*T3[p];
      U[p] = un; V[p] = vn;
      O[idx] = un; O[4096+idx] = vn;
    }
    __syncthreads();
  }
}

__global__ __launch_bounds__(256) void k_kfper(const float* __restrict__ Cin, const float* __restrict__ outyn, float* __restrict__ ws)
{ // per-t: P_pred, S_inv, Kg, G, b_t  (in-place GJ inversion)
  __shared__ float b1[64*LD], b2[64*LD], b3[64*LD];
  const int t = threadIdx.x, tt = blockIdx.x;
  float* base = ws + OFF_UV + (size_t)tt*8192;
  // stage U->b1 and V->b3 (overlapped loads)
  for (int idx = t; idx < 4096; idx += 256) {
    const int r = idx>>6, c = idx&63;
    b1[r*LD+c] = base[idx];             // U
    b3[r*LD+c] = base[4096+idx];        // V
  }
  gji8(t, b1);                          // b1 = U^{-1} (leading sync inside)
  mmNN<64>(t, b2, LD, b3, LD, b1, LD);  // b2 = X = V @ Uinv
  __syncthreads();
  symTile(t, b3, b2);                   // b3 = P_pred = sym(X)  (V dead)
  __syncthreads();
  mmNN<64>(t, b1, LD, Cin, 64, b3, LD); // b1 = CtP = C @ P  (Uinv dead)
  __syncthreads();
  mmTB<64>(t, b2, LD, b1, LD, Cin, 64, ws+OFF_VM, 64); // b2 = Sm = CtP C^T + V
  __syncthreads();
  if (t < 64) b2[t*LD+t] += EPS_C;
  gji8(t, b2);                          // b2 = S_inv (leading sync handles eps write)
  for (int idx = t; idx < 4096; idx += 256) base[4096+idx] = b2[(idx>>6)*LD+(idx&63)];   // store S_inv
  mmTA<64>(t, b3, LD, b1, LD, b2, LD);  // b3 = Kg = CtP^T @ S_inv  (P_pred dead)
  __syncthreads();
  for (int idx = t; idx < 4096; idx += 256) base[idx] = b3[(idx>>6)*LD+(idx&63)];        // store Kg
  mmNN<64>(t, b2, LD, b3, LD, Cin, 64); // b2 = Z = Kg @ C  (S_inv stored)
  __syncthreads();
  // G = Y + DT*Aeff^T@Y, Y = I - Z^T  -> staged in b1 (CtP dead), linear store
  const float* Ae = ws + OFF_AEFF + (size_t)tt*4096;
  float* Gg = ws + OFF_G + (size_t)tt*4096;
  {
    const int r0 = (t>>4)<<2, cg0 = (t&15)<<2;
    float acc[4][4] = {};
    for (int k = 0; k < 64; k += 4) {
      float a_[4][4];   // a_[kk][i] = Aeff[(k+kk)][r0+i]
      #pragma unroll
      for (int kk = 0; kk < 4; ++kk) {
        const float4 x = *(const float4*)&Ae[(k+kk)*64 + r0];
        a_[kk][0]=x.x; a_[kk][1]=x.y; a_[kk][2]=x.z; a_[kk][3]=x.w;
      }
      float yv[4][4];   // yv[j][kk] = Y[k+kk][cg0+j]
      #pragma unroll
      for (int j = 0; j < 4; ++j) {
        const float4 z4 = *(const float4*)&b2[(cg0+j)*LD + k];
        yv[j][0] = -z4.x; yv[j][1] = -z4.y; yv[j][2] = -z4.z; yv[j][3] = -z4.w;
        const int dk = (cg0+j) - k;
        if (dk >= 0 && dk < 4) yv[j][dk] += 1.0f;
      }
      #pragma unroll
      for (int kk = 0; kk < 4; ++kk)
        #pragma unroll
        for (int i = 0; i < 4; ++i) {
          const float a = a_[kk][i];
          #pragma unroll
          for (int j = 0; j < 4; ++j) acc[i][j] += a * yv[j][kk];
        }
    }
    #pragma unroll
    for (int i = 0; i < 4; ++i)
      #pragma unroll
      for (int j = 0; j < 4; ++j) {
        const int rw = r0+i, cw = cg0+j;
        const float Yij = ((rw==cw)?1.f:0.f) - b2[cw*LD + rw];
        b1[rw*LD+cw] = Yij + DT_C*acc[i][j];
      }
  }
  __syncthreads();
  // linear coalesced G store (b1 -> global)
  for (int idx = t; idx < 4096; idx += 256) Gg[idx] = b1[(idx>>6)*LD+(idx&63)];
  // fused b_t = yn_t @ Kg^T  (Kg live in b3; yn streamed from global) -> staged in b2 (Z dead)
  mm32TB<64>(t, b2, LD, outyn + (size_t)tt*64, (size_t)131072, b3, LD);
  __syncthreads();
  float* Bout = ws + OFF_B + (size_t)tt*2048;
  for (int idx = t; idx < 2048; idx += 256) Bout[idx] = b2[(idx>>6)*LD+(idx&63)];
}

__global__ __launch_bounds__(1024) void k_ops3(const float* __restrict__ ws_g, const float* __restrict__ ws_b,
    float* __restrict__ dG, float* __restrict__ dB)
{ // per-chunk x-op product (G, b)
  __shared__ float Gc[64*LD], TG[64*LD], bc[NB*LD], Tb[NB*LD];
  const int t = threadIdx.x, c = blockIdx.x, g = t >> 8, tl = t & 255;
  for (int idx = t; idx < 4096; idx += 1024) {
    const int r = idx>>6, cc = idx&63;
    Gc[r*LD+cc] = (r==cc)?1.f:0.f;
  }
  for (int idx = t; idx < 2048; idx += 1024) bc[(idx>>6)*LD+(idx&63)] = 0.f;
  __syncthreads();
  for (int s = 0; s < CHUNK; ++s) {
    const size_t tt = (size_t)c*CHUNK + s;
    const float* Gt = ws_g + tt*4096;
    if (g == 0)      mmNN<64>(tl, TG, LD, Gc, LD, Gt, 64);
    else if (g == 1) mm32NN<64>(tl, Tb, LD, bc, LD, Gt, 64);
    __syncthreads();
    for (int idx = t; idx < 4096; idx += 1024) {
      const int p = (idx>>6)*LD + (idx&63);
      Gc[p] = TG[p];
    }
    const float* bt = ws_b + tt*2048;
    for (int idx = t; idx < 2048; idx += 1024) {
      const int p = (idx>>6)*LD + (idx&63);
      bc[p] = Tb[p] + bt[idx];
    }
    __syncthreads();
  }
  for (int idx = t; idx < 4096; idx += 1024) dG[(size_t)c*4096 + idx] = Gc[(idx>>6)*LD+(idx&63)];
  for (int idx = t; idx < 2048; idx += 1024) dB[(size_t)c*2048 + idx] = bc[(idx>>6)*LD+(idx&63)];
}

__global__ __launch_bounds__(512) void k_scan3(const float* __restrict__ sG, const float* __restrict__ sB,
    float* __restrict__ dG, float* __restrict__ dB, int s)
{
  const int i = blockIdx.x, t = threadIdx.x, g = t>>8, tl = t&255;
  if (i < s) {
    for (int idx = t; idx < 4096; idx += 512) dG[(size_t)i*4096+idx] = sG[(size_t)i*4096+idx];
    for (int idx = t; idx < 2048; idx += 512) dB[(size_t)i*2048+idx] = sB[(size_t)i*2048+idx];
    return;
  }
  const float* Ge = sG + (size_t)(i-s)*4096;  // earlier
  const float* Gl = sG + (size_t)i*4096;      // later
  if (g == 0) mmNN<64>(tl, dG + (size_t)i*4096, 64, Ge, 64, Gl, 64);                             // G' = Ge @ Gl
  else        mm32NN<64>(tl, dB + (size_t)i*2048, 64, sB + (size_t)(i-s)*2048, 64, Gl, 64,
                         sB + (size_t)i*2048, 64);                                               // b' = be@Gl + bl
}

__global__ __launch_bounds__(256) void k_xb(const float* __restrict__ phiG, const float* __restrict__ phiB,
    const float* __restrict__ x0, float* __restrict__ ws)
{
  __shared__ float v[64];
  const int c = blockIdx.x, t = threadIdx.x;
  float* D = ws + OFF_XB + (size_t)c*2048;
  if (c == 0) {
    for (int idx = t; idx < 2048; idx += 256) D[idx] = x0[idx&63];
    return;
  }
  const float* G = phiG + (size_t)(c-1)*4096;
  const float* b = phiB + (size_t)(c-1)*2048;
  if (t < 64) {
    float acc = 0.f;
    for (int k = 0; k < 64; ++k) acc += x0[k]*G[k*64 + t];
    v[t] = acc;
  }
  __syncthreads();
  for (int idx = t; idx < 2048; idx += 256) D[idx] = v[idx&63] + b[idx];
}

__global__ __launch_bounds__(256) void k_xwalk(const float* __restrict__ ws_g, const float* __restrict__ ws_b,
    const float* __restrict__ ws_xb, float* __restrict__ outx)
{
  __shared__ float x[NB*LD], xn[NB*LD];
  const int c = blockIdx.x, t = threadIdx.x;
  const float* X0 = ws_xb + (size_t)c*2048;
  for (int idx = t; idx < 2048; idx += 256) x[(idx>>6)*LD+(idx&63)] = X0[idx];
  __syncthreads();
  for (int s = 0; s < CHUNK; ++s) {
    const size_t tt = (size_t)c*CHUNK + s;
    mm32NN<64>(t, xn, LD, x, LD, ws_g + tt*4096, 64, ws_b + tt*2048, 64);
    __syncthreads();
    for (int idx = t; idx < 2048; idx += 256) {
      const int i = idx>>6, d = idx&63;
      const float val = xn[i*LD+d];
      x[i*LD+d] = val;
      outx[(size_t)i*131072 + tt*64 + d] = val;
    }
    __syncthreads();
  }
}

__global__ __launch_bounds__(256) void k_final(const float* __restrict__ Cin, const float* __restrict__ x0,
    const float* __restrict__ outx, const float* __restrict__ outyn,
    float* __restrict__ outu, float* __restrict__ outyp, float* __restrict__ ws)
{
  __shared__ float xc[NB*LD], z[NB*LD], t1[NB*LD], t2[NB*LD];
  __shared__ float red4[4];
  const int tt = blockIdx.x, t = threadIdx.x;
  for (int idx = t; idx < 2048; idx += 256) {
    const int i = idx>>6, d = idx&63;
    xc[i*LD+d] = outx[(size_t)i*131072 + (size_t)tt*64 + d];
    z[i*LD+d]  = (tt == 0) ? x0[d] : outx[(size_t)i*131072 + (size_t)(tt-1)*64 + d];
  }
  __syncthreads();
  mm32TB<64>(t, t1, LD, xc, LD, ws + OFF_K + (size_t)tt*4096, 64, nullptr, 0, -1.0f);  // u
  mm32TB<64>(t, t2, LD, xc, LD, Cin, 64);                                              // y_pred
  __syncthreads();
  for (int idx = t; idx < 2048; idx += 256) {
    const int i = idx>>6, d = idx&63;
    outu[(size_t)i*131072 + (size_t)tt*64 + d]  = t1[i*LD+d];
    outyp[(size_t)i*131072 + (size_t)tt*64 + d] = t2[i*LD+d];
  }
  __syncthreads();
  mm32NN<64>(t, t2, LD, xc, LD, ws + OFF_Q, 64);     // x @ Q
  __syncthreads();
  const int i_ = t >> 3, lane8 = t & 7;
  float cpart = 0.f;
  for (int d = lane8; d < 64; d += 8) cpart += t2[i_*LD+d]*xc[i_*LD+d];
  __syncthreads();
  mm32NN<64>(t, t2, LD, t1, LD, ws + OFF_R, 64);     // u @ R
  __syncthreads();
  for (int d = lane8; d < 64; d += 8) cpart += t2[i_*LD+d]*t1[i_*LD+d];
  cpart += __shfl_down(cpart, 4, 8);
  cpart += __shfl_down(cpart, 2, 8);
  cpart += __shfl_down(cpart, 1, 8);
  if (lane8 == 0) ws[OFF_COST + (size_t)tt*32 + i_] = cpart;
  __syncthreads();
  mm32TB<64>(t, t2, LD, z, LD, ws + OFF_AEFF + (size_t)tt*4096, 64, z, LD, DT_C);      // x_pred
  __syncthreads();
  mm32TB<64>(t, t1, LD, t2, LD, Cin, 64, outyn + (size_t)tt*64, (size_t)131072, -1.0f);// resid = yn - x_pred C^T
  __syncthreads();
  mm32TB<64>(t, z, LD, t1, LD, ws + OFF_UV + (size_t)tt*8192 + 4096, 64);              // w = resid @ S_inv^T
  __syncthreads();
  float q = 0.f;
  for (int idx = t; idx < 2048; idx += 256) {
    const int p = (idx>>6)*LD + (idx&63);
    q += t1[p]*z[p];
  }
  q += __shfl_down(q, 32); q += __shfl_down(q, 16); q += __shfl_down(q, 8);
  q += __shfl_down(q, 4);  q += __shfl_down(q, 2);  q += __shfl_down(q, 1);
  if ((t & 63) == 0) red4[t>>6] = q;
  __syncthreads();
  if (t == 0) ws[OFF_QUAD + tt] = red4[0]+red4[1]+red4[2]+red4[3];
}

__global__ __launch_bounds__(256) void k_scalars(const float* __restrict__ ws, float* __restrict__ out)
{
  __shared__ float red[256];
  const int t = threadIdx.x;
  float q = 0.f;
  for (int i = t; i < 2048; i += 256) q += ws[OFF_QUAD + i];
  red[t] = q;
  __syncthreads();
  for (int s = 128; s > 0; s >>= 1) { if (t < s) red[t] += red[t+s]; __syncthreads(); }
  const float quadsum = red[0];
  __syncthreads();
  {
    const int b = t & 31, chunk = t >> 5;
    float a = 0.f;
    for (int j = 0; j < 256; ++j) a += ws[OFF_COST + (size_t)(chunk*256 + j)*32 + b];
    red[t] = a;
  }
  __syncthreads();
  if (t < 32) {
    float a = 0.f;
    for (int ch = 0; ch < 8; ++ch) a += red[ch*32 + t];
    red[t] = a;
  }
  __syncthreads();
  if (t == 0) {
    float cc = 0.f;
    for (int b = 0; b < 32; ++b) cc += red[b];
    out[1] = cc / 32.0f;
    const float ld = ws[OFF_LOGDET];
    out[0] = -0.5f*(quadsum + 2048.0f*(ld + 64.0f*LOG2PI)) / 2048.0f;
  }
}

// =====================================================================
extern "C" void kernel_launch(void* const* d_in, const int* in_sizes, int n_in,
                              void* d_out, int out_size, void* d_ws, size_t ws_size,
                              hipStream_t stream)
{
  (void)in_sizes; (void)n_in; (void)out_size; (void)ws_size;
  const float* y   = (const float*)d_in[0];
  const float* A   = (const float*)d_in[1];
  const float* Bi  = (const float*)d_in[2];
  const float* C   = (const float*)d_in[3];
  const float* LQ  = (const float*)d_in[4];
  const float* LR  = (const float*)d_in[5];
  const float* LV  = (const float*)d_in[6];
  const float* LQp = (const float*)d_in[7];
  const float* x0  = (const float*)d_in[8];
  const float* P0  = (const float*)d_in[9];
  float* out = (float*)d_out;
  float* ws  = (float*)d_ws;

  k_stats<<<256, 256, 0, stream>>>(y, ws);
  k_setup<<<1, 256, 0, stream>>>(A, Bi, LQ, LR, LV, LQp, ws);
  k_yn<<<4096, 256, 0, stream>>>(y, ws, out);

  // chain[j] = M^(2^j), j = 1..11 (16-block parallel squarings)
  for (int j = 1; j <= 11; ++j)
    k_sq<<<16, 256, 0, stream>>>(ws + OFF_CHAIN + (size_t)(j-1)*16384, ws + OFF_CHAIN + (size_t)j*16384);
  // fused power table (M^0..M^63) + boundary states SB_k = M^(64k) S0
  for (int j = 0; j <= 5; ++j)
    k_powbounds<<<6 << j, 256, 0, stream>>>(ws + OFF_CHAIN, ws, j);

  k_lqr<<<2048, 256, 0, stream>>>(A, Bi, ws);

  // KF covariance operator scan (OPS2 ping-pong aliased into the UV region,
  // which is dead until k_uvwalk writes it)
  k_ops2<<<NCH, 1024, 0, stream>>>(ws + OFF_AEFF, ws + OFF_QP, ws + OFF_OPS2);
  {
    float* pa = ws + OFF_OPS2;
    float* pb = pa + (size_t)NCH*12288;
    float* src = pa; float* dst = pb;
    for (int s = 1; s < NCH; s <<= 1) {
      k_scan2<<<NCH, 1024, 0, stream>>>(src, dst, s);
      float* tmp = src; src = dst; dst = tmp;
    }
    k_sb2<<<NCH, 256, 0, stream>>>(src, P0, ws);
  }
  k_uvwalk<<<NCH, 1024, 0, stream>>>(ws + OFF_AEFF, ws + OFF_QP, ws + OFF_SB2, ws + OFF_UV);
  k_kfper<<<2048, 256, 0, stream>>>(C, out + OOFF_YN, ws);

  // x-filter affine scan
  k_ops3<<<NCH, 1024, 0, stream>>>(ws + OFF_G, ws + OFF_B, ws + OFF_OPS3G, ws + OFF_OPS3B);
  {
    float* ga = ws + OFF_OPS3G; float* gb = ga + (size_t)NCH*4096;
    float* ba = ws + OFF_OPS3B; float* bb = ba + (size_t)NCH*2048;
    float *gs = ga, *gd = gb, *bs = ba, *bd = bb;
    for (int s = 1; s < NCH; s <<= 1) {
      k_scan3<<<NCH, 512, 0, stream>>>(gs, bs, gd, bd, s);
      float* t1p = gs; gs = gd; gd = t1p;
      float* t2p = bs; bs = bd; bd = t2p;
    }
    k_xb<<<NCH, 256, 0, stream>>>(gs, bs, x0, ws);
  }
  k_xwalk<<<NCH, 256, 0, stream>>>(ws + OFF_G, ws + OFF_B, ws + OFF_XB, out + OOFF_XF);

  // epilogue
  k_final<<<2048, 256, 0, stream>>>(C, x0, out + OOFF_XF, out + OOFF_YN, out + OOFF_U, out + OOFF_YP, ws);
  k_scalars<<<1, 256, 0, stream>>>(ws, out);
}